// Round 7
// baseline (5304.992 us; speedup 1.0000x reference)
//
#include <hip/hip_runtime.h>

// B=2, streams=2, N=1024, D=256, H=4, DH=64, L=18
// Row layout: r = s*2048 + b*1024 + n  (M=4096 rows)
// bf16 MFMA 16x16x32: A-frag lane=A[m=lane&15][k=quad*8+j]; B-frag B[k=quad*8+j][n=lane&15]
// C/D: col=lane&15, row=quad*4+reg
// LDS XOR swizzle: 16B chunk c of row r stored at slot (c ^ (r&7)).
// Persistent mega-kernel: 256 blocks (1/CU), hand-rolled device-scope grid barrier.

typedef __attribute__((ext_vector_type(8))) short bf16x8;
typedef __attribute__((ext_vector_type(4))) short bf16x4;
typedef __attribute__((ext_vector_type(4))) float floatx4;

__device__ __forceinline__ short f2b(float f) {   // fp32 -> bf16 RNE
  unsigned u = __builtin_bit_cast(unsigned, f);
  unsigned r = (u + 0x7FFFu + ((u >> 16) & 1u)) >> 16;
  return (short)r;
}
__device__ __forceinline__ unsigned pack2(float a, float b) {
  return (unsigned)(unsigned short)f2b(a) | ((unsigned)(unsigned short)f2b(b) << 16);
}

__device__ __forceinline__ void gl2lds16(const void* g, void* l) {
  __builtin_amdgcn_global_load_lds(
      (const __attribute__((address_space(1))) unsigned*)g,
      (__attribute__((address_space(3))) unsigned*)l, 16, 0, 0);
}

__device__ __forceinline__ floatx4 mfma16_bf16(bf16x4 a, bf16x4 b, floatx4 c) {
#if __has_builtin(__builtin_amdgcn_mfma_f32_16x16x16_bf16)
  return __builtin_amdgcn_mfma_f32_16x16x16_bf16(a, b, c, 0, 0, 0);
#elif __has_builtin(__builtin_amdgcn_mfma_f32_16x16x16bf16_1k)
  return __builtin_amdgcn_mfma_f32_16x16x16bf16_1k(a, b, c, 0, 0, 0);
#else
  asm volatile("v_mfma_f32_16x16x16_bf16 %0, %1, %2, %0" : "+v"(c) : "v"(a), "v"(b));
  return c;
#endif
}

// device-scope sense-reversing grid barrier (all 256 blocks must call).
__device__ __forceinline__ void gsync(unsigned* cnt, unsigned* gen) {
  __syncthreads();
  if (threadIdx.x == 0) {
    __threadfence();   // flush this block's writes device-wide
    unsigned g = __hip_atomic_load(gen, __ATOMIC_RELAXED, __HIP_MEMORY_SCOPE_AGENT);
    unsigned a = __hip_atomic_fetch_add(cnt, 1u, __ATOMIC_ACQ_REL, __HIP_MEMORY_SCOPE_AGENT);
    if (a == 255u) {
      __hip_atomic_store(cnt, 0u, __ATOMIC_RELAXED, __HIP_MEMORY_SCOPE_AGENT);
      __hip_atomic_store(gen, g + 1u, __ATOMIC_RELEASE, __HIP_MEMORY_SCOPE_AGENT);
    } else {
      while (__hip_atomic_load(gen, __ATOMIC_ACQUIRE, __HIP_MEMORY_SCOPE_AGENT) == g)
        __builtin_amdgcn_s_sleep(2);
    }
    __threadfence();   // invalidate caches before reading others' writes
  }
  __syncthreads();
}

// ---------- input copy with (s,b) swap; writes fp32 residual + bf16 copy
__global__ __launch_bounds__(256) void swap_copy_in(const float* __restrict__ src,
                                                    float* __restrict__ xd,
                                                    short* __restrict__ xb) {
  int idx = blockIdx.x * 256 + threadIdx.x;
  int fi = idx << 2;
  int hi = (fi >> 19) & 1;
  int lo = (fi >> 18) & 1;
  int sj = (fi & ~(3 << 18)) | (lo << 19) | (hi << 18);
  float4 v = *(const float4*)&src[sj];
  *(float4*)&xd[fi] = v;
  uint2 uu; uu.x = pack2(v.x, v.y); uu.y = pack2(v.z, v.w);
  *(uint2*)&xb[fi] = uu;
}

__global__ __launch_bounds__(256) void swap_copy_out(const float* __restrict__ src,
                                                     float* __restrict__ dst) {
  int idx = blockIdx.x * 256 + threadIdx.x;
  int fi = idx << 2;
  int hi = (fi >> 19) & 1;
  int lo = (fi >> 18) & 1;
  int sj = (fi & ~(3 << 18)) | (lo << 19) | (hi << 18);
  *(float4*)&dst[fi] = *(const float4*)&src[sj];
}

// ---------- weight transpose + convert: Wt[n][k]. 112 blocks/layer.
// per-layer wbuf (shorts): qwt@0 kwt@65536 vwt@131072 w1t@262144(512x512) w2t@524288
__global__ __launch_bounds__(256) void wconv(
    const float* __restrict__ qw, const float* __restrict__ kw,
    const float* __restrict__ vw, const float* __restrict__ w1,
    const float* __restrict__ w2, short* __restrict__ wbuf, int layer0) {
  __shared__ float T[64][65];
  int blk = blockIdx.x;
  int layer = layer0 + blk / 112;
  int sub = blk % 112;
  const float* W; int Kd, Nd, k0, n0; size_t ooff;
  if (sub < 48) {
    int wsel = sub >> 4; int t = sub & 15;
    k0 = (t >> 2) * 64; n0 = (t & 3) * 64; Kd = 256; Nd = 256;
    W = (wsel == 0 ? qw : wsel == 1 ? kw : vw) + (size_t)layer * 65536;
    ooff = (size_t)wsel * 65536;
  } else if (sub < 80) {
    int t = sub - 48; k0 = (t >> 3) * 64; n0 = (t & 7) * 64;   // k0<256 (top half)
    Kd = 512; Nd = 512; W = w1 + (size_t)layer * 262144; ooff = 262144;
  } else {
    int t = sub - 80; k0 = (t >> 2) * 64; n0 = (t & 3) * 64;
    Kd = 512; Nd = 256; W = w2 + (size_t)layer * 131072; ooff = 524288;
  }
  short* out = wbuf + (size_t)(layer - layer0) * 655360 + ooff;
  int t = threadIdx.x;
  int r = t >> 4, c4 = (t & 15) * 4;
#pragma unroll
  for (int rr = 0; rr < 4; ++rr) {
    float4 v = *(const float4*)&W[(size_t)(k0 + r + rr * 16) * Nd + n0 + c4];
    T[r + rr * 16][c4 + 0] = v.x; T[r + rr * 16][c4 + 1] = v.y;
    T[r + rr * 16][c4 + 2] = v.z; T[r + rr * 16][c4 + 3] = v.w;
  }
  __syncthreads();
  int n = t >> 2, kc = (t & 3) * 16;
  unsigned u[8];
#pragma unroll
  for (int j2 = 0; j2 < 8; ++j2)
    u[j2] = pack2(T[kc + 2 * j2][n], T[kc + 2 * j2 + 1][n]);
  short* op = &out[(size_t)(n0 + n) * Kd + k0 + kc];
  uint4 o1; o1.x = u[0]; o1.y = u[1]; o1.z = u[2]; o1.w = u[3];
  uint4 o2; o2.x = u[4]; o2.y = u[5]; o2.z = u[6]; o2.w = u[7];
  *(uint4*)&op[0] = o1;
  *(uint4*)&op[8] = o2;
}

// ---------- fused weight: F = ow @ w1[256:512]; F^T into w1t[n][256+k'].
__global__ __launch_bounds__(256) void wfuse(
    const float* __restrict__ ow, const float* __restrict__ w1,
    short* __restrict__ wbuf, int layer0) {
  __shared__ float As[16][64];
  __shared__ float Bs[16][65];
  int blk = blockIdx.x;
  int layer = layer0 + blk / 32;
  int sub = blk % 32;
  int n0 = (sub & 7) * 64, kp0 = (sub >> 3) * 64;
  const float* A = ow + (size_t)layer * 65536 + (size_t)kp0 * 256;     // [kp][i]
  const float* B = w1 + (size_t)layer * 262144 + 256 * 512 + n0;      // [i][n]
  const int tid = threadIdx.x;
  const int tx = tid & 15, ty = tid >> 4;
  const int a_r = tid >> 2, a_k = (tid & 3) << 2;
  const int b_k = tid >> 4, b_n = (tid & 15) << 2;
  float acc[4][4];
#pragma unroll
  for (int i = 0; i < 4; ++i)
#pragma unroll
    for (int j = 0; j < 4; ++j) acc[i][j] = 0.f;
  for (int i0 = 0; i0 < 256; i0 += 16) {
    float4 av = *(const float4*)&A[(size_t)a_r * 256 + i0 + a_k];
    float4 bv = *(const float4*)&B[(size_t)(i0 + b_k) * 512 + b_n];
    __syncthreads();
    As[a_k + 0][a_r] = av.x; As[a_k + 1][a_r] = av.y;
    As[a_k + 2][a_r] = av.z; As[a_k + 3][a_r] = av.w;
    *(float4*)&Bs[b_k][b_n] = bv;
    __syncthreads();
#pragma unroll
    for (int kk = 0; kk < 16; ++kk) {
      float4 a4 = *(const float4*)&As[kk][ty << 2];
      float4 b4 = *(const float4*)&Bs[kk][tx << 2];
      float aa[4] = {a4.x, a4.y, a4.z, a4.w};
      float bb[4] = {b4.x, b4.y, b4.z, b4.w};
#pragma unroll
      for (int i = 0; i < 4; ++i)
#pragma unroll
        for (int j = 0; j < 4; ++j) acc[i][j] += aa[i] * bb[j];
    }
  }
  short* w1t = wbuf + (size_t)(layer - layer0) * 655360 + 262144;
#pragma unroll
  for (int i = 0; i < 4; ++i)
#pragma unroll
    for (int j = 0; j < 4; ++j)
      w1t[(size_t)(n0 + tx * 4 + j) * 512 + 256 + kp0 + ty * 4 + i] = f2b(acc[i][j]);
}

// ---------- fused bias: beff[l][n] = b1[l][n] + sum_i ob[l][i]*w1[l][256+i][n]
__global__ __launch_bounds__(256) void bfuse(
    const float* __restrict__ ob, const float* __restrict__ w1,
    const float* __restrict__ b1, float* __restrict__ beff, int layer0) {
  int layer = layer0 + blockIdx.x;
  const float* obL = ob + (size_t)layer * 256;
  const float* w1L = w1 + (size_t)layer * 262144 + 256 * 512;
  float* be = beff + (size_t)blockIdx.x * 512;
#pragma unroll
  for (int cc = 0; cc < 2; ++cc) {
    int n = threadIdx.x + cc * 256;
    float s = b1[(size_t)layer * 512 + n];
    for (int i = 0; i < 256; ++i) s += obL[i] * w1L[(size_t)i * 512 + n];
    be[n] = s;
  }
}

#define GEMM_IDS                                        \
  const int tid = threadIdx.x;                          \
  const int lane = tid & 63, w = tid >> 6;              \
  const int wy = w >> 1, wx = w & 1;                    \
  const int quad = lane >> 4, l16 = lane & 15;          \
  const int lr = lane >> 3;                             \
  const int lcs = (((lane & 7) ^ lr) & 7) * 8;          \
  const floatx4 z4 = {0.f, 0.f, 0.f, 0.f};              \
  floatx4 acc[2][4] = {{z4, z4, z4, z4}, {z4, z4, z4, z4}};

// swizzled MFMA K-step (BM=64, BN=128, wave-tile 32x64)
__device__ __forceinline__ void mfma_step_sw(const short* As, const short* Bs,
                                             int wy, int wx, int quad, int l16,
                                             floatx4 acc[2][4]) {
#pragma unroll
  for (int kk = 0; kk < 2; ++kk) {
    const int sw = (((kk * 4 + quad) ^ (l16 & 7)) * 8);
    bf16x8 a0 = *(const bf16x8*)&As[(wy * 32 + l16) * 64 + sw];
    bf16x8 a1 = *(const bf16x8*)&As[(wy * 32 + 16 + l16) * 64 + sw];
    bf16x8 b[4];
#pragma unroll
    for (int ni = 0; ni < 4; ++ni)
      b[ni] = *(const bf16x8*)&Bs[(wx * 64 + ni * 16 + l16) * 64 + sw];
#pragma unroll
    for (int ni = 0; ni < 4; ++ni) {
      acc[0][ni] = __builtin_amdgcn_mfma_f32_16x16x32_bf16(a0, b[ni], acc[0][ni], 0, 0, 0);
      acc[1][ni] = __builtin_amdgcn_mfma_f32_16x16x32_bf16(a1, b[ni], acc[1][ni], 0, 0, 0);
    }
  }
}

// ---------- phase: fused QKV GEMM (tiles 0..383); v-seg writes V^T
__device__ __forceinline__ void phase_qkv(
    int t, short* SM, const short* __restrict__ xb, const short* __restrict__ wbufL,
    const float* __restrict__ qb_, const float* __restrict__ kb_,
    const float* __restrict__ vb_, short* __restrict__ q,
    short* __restrict__ kout, short* __restrict__ vT, int cross) {
  short* As = SM;            // [2][4096]
  short* Bs = SM + 8192;     // [2][8192]
  const int rb = (t & 63) * 64;
  const int cb = (t >> 6) * 128;
  const int seg = cb >> 8;
  const int cbl = cb & 255;
  int arb = rb;
  if (seg) arb = (rb & 2047) | ((((rb >> 11) ^ cross) & 1) << 11);
  const short* A = xb + (size_t)arb * 256;
  const short* Wt = wbufL + (size_t)seg * 65536 + (size_t)cbl * 256;
  const float* bias = (seg == 0 ? qb_ : seg == 1 ? kb_ : vb_) + cbl;
  GEMM_IDS;
  __syncthreads();   // protect LDS reuse across a block's consecutive tiles

#define QKV_STAGE(s, buf)                                                          \
  {                                                                                \
    int k0 = (s) * 64;                                                             \
    gl2lds16(&A[(size_t)(w * 8 + lr) * 256 + k0 + lcs], &As[(buf) * 4096 + (w * 8) * 64]); \
    gl2lds16(&A[(size_t)(32 + w * 8 + lr) * 256 + k0 + lcs], &As[(buf) * 4096 + (32 + w * 8) * 64]); \
    _Pragma("unroll") for (int i = 0; i < 4; ++i)                                  \
      gl2lds16(&Wt[(size_t)(i * 32 + w * 8 + lr) * 256 + k0 + lcs],                \
               &Bs[(buf) * 8192 + (i * 32 + w * 8) * 64]);                         \
  }

  QKV_STAGE(0, 0);
  __syncthreads();
  for (int s = 0; s < 4; ++s) {
    int buf = s & 1;
    if (s < 3) QKV_STAGE(s + 1, buf ^ 1);
    mfma_step_sw(&As[buf * 4096], &Bs[buf * 8192], wy, wx, quad, l16, acc);
    __syncthreads();
  }

  if (seg < 2) {
    short* C = (seg == 0 ? q : kout) + (size_t)rb * 256 + cbl;
#pragma unroll
    for (int mi = 0; mi < 2; ++mi)
#pragma unroll
      for (int ni = 0; ni < 4; ++ni) {
        int col = wx * 64 + ni * 16 + l16;
        float bc = bias[col];
#pragma unroll
        for (int reg = 0; reg < 4; ++reg) {
          int row = wy * 32 + mi * 16 + quad * 4 + reg;
          C[(size_t)row * 256 + col] = f2b(acc[mi][ni][reg] + bc);
        }
      }
  } else {
    short* T = SM + w * 2560;       // 64 dims x 40 (pad), wave-local
    const int sb = rb >> 10;
    const int hh = (cbl >> 6) + wx;
    const int z = sb * 4 + hh;
#pragma unroll
    for (int mi = 0; mi < 2; ++mi)
#pragma unroll
      for (int ni = 0; ni < 4; ++ni) {
        int col = wx * 64 + ni * 16 + l16;
        float bc = bias[col];
#pragma unroll
        for (int reg = 0; reg < 4; ++reg)
          T[(ni * 16 + l16) * 40 + mi * 16 + quad * 4 + reg] =
              f2b(acc[mi][ni][reg] + bc);
      }
    short* dst = &vT[((size_t)z * 64 + lane) * 1024 + (rb & 1023) + wy * 32];
#pragma unroll
    for (int c = 0; c < 4; ++c)
      *(uint4*)&dst[c * 8] = *(const uint4*)&T[lane * 40 + c * 8];
  }
#undef QKV_STAGE
}

// ---------- phase: flash attention, S^T/O^T form (tiles 0..255)
__device__ __forceinline__ void phase_attn(
    int t0_, short* SM, float* EX, const short* __restrict__ q,
    const short* __restrict__ k, const short* __restrict__ vT,
    const int* __restrict__ mask, short* __restrict__ attnb, int cross) {
  short* Ks = SM;            // [2][4096]
  short* Vs = SM + 8192;     // [2][4096]
  float* Ms = EX;            // [2][64]
  const int tid = threadIdx.x;
  const int lane = tid & 63, w = tid >> 6;
  const int quad = lane >> 4, l16 = lane & 15;
  const int lr = lane >> 3;
  const int lcs = (((lane & 7) ^ lr) & 7) * 8;
  const int qt = t0_ & 15;
  const int z = t0_ >> 4;
  const int sb = z >> 2, h = z & 3;
  const int s = sb >> 1, b = sb & 1;
  const int rowbase = sb * 1024;
  const int* mp = mask + (b * 2 + (s ^ cross)) * 1024;

  const int qrow = qt * 64 + w * 16 + l16;
  bf16x8 qf[2];
#pragma unroll
  for (int kk = 0; kk < 2; ++kk)
    qf[kk] = *(const bf16x8*)&q[(size_t)(rowbase + qrow) * 256 + h * 64 + kk * 32 + quad * 8];

  const floatx4 z4 = {0.f, 0.f, 0.f, 0.f};
  floatx4 o4[4] = {z4, z4, z4, z4};
  float mrun = -1e30f, lsum = 0.f;

#define ATT_STAGE(t, buf)                                                               \
  {                                                                                     \
    int key0 = (t) * 64;                                                                \
    gl2lds16(&k[(size_t)(rowbase + key0 + w * 8 + lr) * 256 + h * 64 + lcs],            \
             &Ks[(buf) * 4096 + (w * 8) * 64]);                                         \
    gl2lds16(&k[(size_t)(rowbase + key0 + 32 + w * 8 + lr) * 256 + h * 64 + lcs],       \
             &Ks[(buf) * 4096 + (32 + w * 8) * 64]);                                    \
    gl2lds16(&vT[((size_t)z * 64 + w * 8 + lr) * 1024 + key0 + lcs],                    \
             &Vs[(buf) * 4096 + (w * 8) * 64]);                                         \
    gl2lds16(&vT[((size_t)z * 64 + 32 + w * 8 + lr) * 1024 + key0 + lcs],               \
             &Vs[(buf) * 4096 + (32 + w * 8) * 64]);                                    \
    if (tid < 64) Ms[(buf) * 64 + tid] = (mp[key0 + tid] == 0) ? -1.0e9f : 0.f;         \
  }

  __syncthreads();
  ATT_STAGE(0, 0);
  __syncthreads();
  for (int t = 0; t < 16; ++t) {
    int buf = t & 1;
    if (t < 15) ATT_STAGE(t + 1, buf ^ 1);

    floatx4 sA[4] = {z4, z4, z4, z4};
#pragma unroll
    for (int kk = 0; kk < 2; ++kk) {
      const int sw = (((kk * 4 + quad) ^ (l16 & 7)) * 8);
#pragma unroll
      for (int mt = 0; mt < 4; ++mt) {
        bf16x8 kf = *(const bf16x8*)&Ks[buf * 4096 + (mt * 16 + l16) * 64 + sw];
        sA[mt] = __builtin_amdgcn_mfma_f32_16x16x32_bf16(kf, qf[kk], sA[mt], 0, 0, 0);
      }
    }
    float scv[4][4];
    float tmax = -1e30f;
#pragma unroll
    for (int mt = 0; mt < 4; ++mt) {
      float4 mk = *(const float4*)&Ms[buf * 64 + mt * 16 + quad * 4];
      scv[mt][0] = sA[mt][0] * 0.125f + mk.x;
      scv[mt][1] = sA[mt][1] * 0.125f + mk.y;
      scv[mt][2] = sA[mt][2] * 0.125f + mk.z;
      scv[mt][3] = sA[mt][3] * 0.125f + mk.w;
#pragma unroll
      for (int reg = 0; reg < 4; ++reg) tmax = fmaxf(tmax, scv[mt][reg]);
    }
    tmax = fmaxf(tmax, __shfl_xor(tmax, 16));
    tmax = fmaxf(tmax, __shfl_xor(tmax, 32));
    float mnew = fmaxf(mrun, tmax);
    float corr = __expf(mrun - mnew);
    mrun = mnew;
    lsum *= corr;
#pragma unroll
    for (int dt = 0; dt < 4; ++dt)
#pragma unroll
      for (int reg = 0; reg < 4; ++reg) o4[dt][reg] *= corr;

    bf16x4 pb[4];
#pragma unroll
    for (int mt = 0; mt < 4; ++mt) {
      float e0 = __expf(scv[mt][0] - mnew);
      float e1 = __expf(scv[mt][1] - mnew);
      float e2 = __expf(scv[mt][2] - mnew);
      float e3 = __expf(scv[mt][3] - mnew);
      lsum += (e0 + e1) + (e2 + e3);
      union { bf16x4 v; uint2 u; } pu;
      pu.u.x = pack2(e0, e1); pu.u.y = pack2(e2, e3);
      pb[mt] = pu.v;
    }
#pragma unroll
    for (int mt = 0; mt < 4; ++mt) {
      const int c2 = mt * 2 + (quad >> 1);
      const int sub = (quad & 1) * 4;
#pragma unroll
      for (int dt = 0; dt < 4; ++dt) {
        bf16x4 vf = *(const bf16x4*)&Vs[buf * 4096 + (dt * 16 + l16) * 64 +
                                        ((c2 ^ (l16 & 7)) * 8) + sub];
        o4[dt] = mfma16_bf16(vf, pb[mt], o4[dt]);
      }
    }
    __syncthreads();
  }
  lsum += __shfl_xor(lsum, 16);
  lsum += __shfl_xor(lsum, 32);
  float inv = 1.f / lsum;
  short* op = &attnb[(size_t)(rowbase + qrow) * 256 + h * 64 + quad * 4];
#pragma unroll
  for (int dt = 0; dt < 4; ++dt) {
    uint2 uu;
    uu.x = pack2(o4[dt][0] * inv, o4[dt][1] * inv);
    uu.y = pack2(o4[dt][2] * inv, o4[dt][3] * inv);
    *(uint2*)&op[dt * 16] = uu;
  }
#undef ATT_STAGE
}

// ---------- phase: W1 GEMM + BN column partials (tiles 0..255)
__device__ __forceinline__ void phase_w1(
    int t0_, short* SM, float* EX, const short* __restrict__ xb,
    const short* __restrict__ attnb, const short* __restrict__ w1t,
    const float* __restrict__ beff, float* __restrict__ hbuf,
    float* __restrict__ psum, float* __restrict__ psq) {
  short* As = SM;
  short* Bs = SM + 8192;
  float* Ps = EX;    // [2][2][128] linear
  const int rbId = t0_ & 63;
  const int rb = rbId * 64, cb = (t0_ >> 6) * 128;
  GEMM_IDS;

#define W1_STAGE(s, buf)                                                            \
  {                                                                                 \
    int k0 = (s) * 64;                                                              \
    const short* Ap = ((s) < 4 ? xb : attnb) + (size_t)rb * 256;                    \
    int kb = k0 & 255;                                                              \
    gl2lds16(&Ap[(size_t)(w * 8 + lr) * 256 + kb + lcs], &As[(buf) * 4096 + (w * 8) * 64]); \
    gl2lds16(&Ap[(size_t)(32 + w * 8 + lr) * 256 + kb + lcs], &As[(buf) * 4096 + (32 + w * 8) * 64]); \
    _Pragma("unroll") for (int i = 0; i < 4; ++i)                                   \
      gl2lds16(&w1t[(size_t)(cb + i * 32 + w * 8 + lr) * 512 + k0 + lcs],           \
               &Bs[(buf) * 8192 + (i * 32 + w * 8) * 64]);                          \
  }

  __syncthreads();
  W1_STAGE(0, 0);
  __syncthreads();
  for (int s = 0; s < 8; ++s) {
    int buf = s & 1;
    if (s < 7) W1_STAGE(s + 1, buf ^ 1);
    mfma_step_sw(&As[buf * 4096], &Bs[buf * 8192], wy, wx, quad, l16, acc);
    __syncthreads();
  }
  float colsum[4], colsq[4];
#pragma unroll
  for (int ni = 0; ni < 4; ++ni) { colsum[ni] = 0.f; colsq[ni] = 0.f; }
#pragma unroll
  for (int mi = 0; mi < 2; ++mi)
#pragma unroll
    for (int ni = 0; ni < 4; ++ni) {
      int col = wx * 64 + ni * 16 + l16;
      float bc = beff[cb + col];
#pragma unroll
      for (int reg = 0; reg < 4; ++reg) {
        int row = rb + wy * 32 + mi * 16 + quad * 4 + reg;
        float val = acc[mi][ni][reg] + bc;
        hbuf[(size_t)row * 512 + cb + col] = val;
        colsum[ni] += val; colsq[ni] += val * val;
      }
    }
#pragma unroll
  for (int ni = 0; ni < 4; ++ni)
#pragma unroll
    for (int d = 16; d < 64; d <<= 1) {
      colsum[ni] += __shfl_xor(colsum[ni], d);
      colsq[ni]  += __shfl_xor(colsq[ni], d);
    }
  if (quad == 0) {
#pragma unroll
    for (int ni = 0; ni < 4; ++ni) {
      Ps[(wy * 2 + 0) * 128 + wx * 64 + ni * 16 + l16] = colsum[ni];
      Ps[(wy * 2 + 1) * 128 + wx * 64 + ni * 16 + l16] = colsq[ni];
    }
  }
  __syncthreads();
  if (tid < 128) {
    psum[(size_t)(cb + tid) * 64 + rbId] = Ps[tid] + Ps[256 + tid];
    psq [(size_t)(cb + tid) * 64 + rbId] = Ps[128 + tid] + Ps[384 + tid];
  }
#undef W1_STAGE
}

// ---------- phase: W2 GEMM, BN finalize + fused BN/ReLU A-staging + residual (tiles 0..127)
__device__ __forceinline__ void phase_w2(
    int t0_, short* SM, float* EX, const float* __restrict__ hbuf,
    const short* __restrict__ w2t, const float* __restrict__ b2_,
    const float* __restrict__ psum, const float* __restrict__ psq,
    const float* __restrict__ g, const float* __restrict__ be,
    float* __restrict__ xd, short* __restrict__ xb) {
  short* As = SM;
  short* Bs = SM + 8192;
  float* s_scale = EX;        // [512]
  float* s_shift = EX + 512;  // [512]
  const int rbId = t0_ & 63;
  const int rb = rbId * 64, cb = (t0_ >> 6) * 128;
  const int str = rbId >> 5;
  GEMM_IDS;
  __syncthreads();
#pragma unroll
  for (int cc = 0; cc < 2; ++cc) {
    int c = tid + cc * 256;
    float sum = 0.f, sq = 0.f;
#pragma unroll
    for (int g4 = 0; g4 < 8; ++g4) {
      float4 a  = *(const float4*)&psum[(size_t)c * 64 + str * 32 + g4 * 4];
      float4 bq = *(const float4*)&psq [(size_t)c * 64 + str * 32 + g4 * 4];
      sum += a.x + a.y + a.z + a.w;
      sq  += bq.x + bq.y + bq.z + bq.w;
    }
    float mean = sum * (1.f / 2048.f);
    float var = sq * (1.f / 2048.f) - mean * mean;
    float rstd = rsqrtf(var + 1e-5f);
    float gs = g[c] * rstd;
    s_scale[c] = gs;
    s_shift[c] = be[c] - mean * gs;
  }
  __syncthreads();

  const int p = tid & 7, ar = tid >> 3;

#define W2_STAGE_A(s, buf)                                                         \
  {                                                                                \
    int k0 = (s) * 64;                                                             \
    _Pragma("unroll") for (int half = 0; half < 2; ++half) {                       \
      int row = ar + half * 32;                                                    \
      int cs = k0 + ((p ^ (row & 7)) * 8);                                         \
      float4 h0 = *(const float4*)&hbuf[(size_t)(rb + row) * 512 + cs];            \
      float4 h1 = *(const float4*)&hbuf[(size_t)(rb + row) * 512 + cs + 4];        \
      float4 sc0 = *(const float4*)&s_scale[cs];                                   \
      float4 sc1 = *(const float4*)&s_scale[cs + 4];                               \
      float4 sh0 = *(const float4*)&s_shift[cs];                                   \
      float4 sh1 = *(const float4*)&s_shift[cs + 4];                               \
      uint4 pk;                                                                    \
      pk.x = pack2(fmaxf(h0.x * sc0.x + sh0.x, 0.f), fmaxf(h0.y * sc0.y + sh0.y, 0.f)); \
      pk.y = pack2(fmaxf(h0.z * sc0.z + sh0.z, 0.f), fmaxf(h0.w * sc0.w + sh0.w, 0.f)); \
      pk.z = pack2(fmaxf(h1.x * sc1.x + sh1.x, 0.f), fmaxf(h1.y * sc1.y + sh1.y, 0.f)); \
      pk.w = pack2(fmaxf(h1.z * sc1.z + sh1.z, 0.f), fmaxf(h1.w * sc1.w + sh1.w, 0.f)); \
      *(uint4*)&As[(buf) * 4096 + row * 64 + p * 8] = pk;                          \
    }                                                                              \
  }
#define W2_STAGE_B(s, buf)                                                         \
  {                                                                                \
    int k0 = (s) * 64;                                                             \
    _Pragma("unroll") for (int i = 0; i < 4; ++i)                                  \
      gl2lds16(&w2t[(size_t)(cb + i * 32 + w * 8 + lr) * 512 + k0 + lcs],          \
               &Bs[(buf) * 8192 + (i * 32 + w * 8) * 64]);                         \
  }

  W2_STAGE_A(0, 0);
  W2_STAGE_B(0, 0);
  __syncthreads();
  for (int s = 0; s < 8; ++s) {
    int buf = s & 1;
    if (s < 7) W2_STAGE_B(s + 1, buf ^ 1);
    mfma_step_sw(&As[buf * 4096], &Bs[buf * 8192], wy, wx, quad, l16, acc);
    if (s < 7) W2_STAGE_A(s + 1, buf ^ 1);
    __syncthreads();
  }
#pragma unroll
  for (int mi = 0; mi < 2; ++mi)
#pragma unroll
    for (int ni = 0; ni < 4; ++ni) {
      int col = cb + wx * 64 + ni * 16 + l16;
      float bc = b2_[col];
#pragma unroll
      for (int reg = 0; reg < 4; ++reg) {
        int row = rb + wy * 32 + mi * 16 + quad * 4 + reg;
        float r = xd[(size_t)row * 256 + col] + acc[mi][ni][reg] + bc;
        xd[(size_t)row * 256 + col] = r;
        xb[(size_t)row * 256 + col] = f2b(r);
      }
    }
#undef W2_STAGE_A
#undef W2_STAGE_B
}

// ---------- persistent mega-kernel: all 18 layers, manual grid barrier
struct MegaArgs {
  const int* mask;
  const float* qb; const float* kb; const float* vb;
  const float* b2; const float* bn_g; const float* bn_b;
  float* xd; short* xb;
  short* qb16; short* kb16; short* vTb; short* attnb;
  float* hbuf; float* psum; float* psq; const float* beff;
  const short* wbuf;
  unsigned* bar;     // [0]=cnt, [1]=gen (pre-zeroed via hipMemsetAsync)
};

__global__ __launch_bounds__(256, 1) void mega(MegaArgs a) {
  __shared__ __align__(16) short SM[24576];   // 48 KB staging union
  __shared__ __align__(16) float EX[1024];    // 4 KB (Ms / Ps / scale+shift)
  unsigned* cnt = a.bar;
  unsigned* gen = a.bar + 1;
  const int bid = blockIdx.x;

  for (int i = 0; i < 18; ++i) {
    const int cross = i & 1;
    const short* wb = a.wbuf + (size_t)i * 655360;

    for (int t = bid; t < 384; t += 256)
      phase_qkv(t, SM, a.xb, wb, a.qb + (size_t)i * 256, a.kb + (size_t)i * 256,
                a.vb + (size_t)i * 256, a.qb16, a.kb16, a.vTb, cross);
    gsync(cnt, gen);

    phase_attn(bid, SM, EX, a.qb16, a.kb16, a.vTb, a.mask, a.attnb, cross);
    gsync(cnt, gen);

    phase_w1(bid, SM, EX, a.xb, a.attnb, wb + 262144, a.beff + (size_t)i * 512,
             a.hbuf, a.psum, a.psq);
    gsync(cnt, gen);

    if (bid < 128)
      phase_w2(bid, SM, EX, a.hbuf, wb + 524288, a.b2 + (size_t)i * 256,
               a.psum, a.psq, a.bn_g + (size_t)i * 512, a.bn_b + (size_t)i * 512,
               a.xd, a.xb);
    gsync(cnt, gen);
  }
}

extern "C" void kernel_launch(void* const* d_in, const int* in_sizes, int n_in,
                              void* d_out, int out_size, void* d_ws, size_t ws_size,
                              hipStream_t stream) {
  (void)in_sizes; (void)n_in; (void)out_size; (void)ws_size;
  const float* desc = (const float*)d_in[0];
  const int*   mask = (const int*)d_in[1];
  const float* qw = (const float*)d_in[2];
  const float* qb = (const float*)d_in[3];
  const float* kw = (const float*)d_in[4];
  const float* kb = (const float*)d_in[5];
  const float* vw = (const float*)d_in[6];
  const float* vb = (const float*)d_in[7];
  const float* ow = (const float*)d_in[8];
  const float* ob = (const float*)d_in[9];
  const float* w1 = (const float*)d_in[10];
  const float* b1 = (const float*)d_in[11];
  const float* bn_g = (const float*)d_in[12];
  const float* bn_b = (const float*)d_in[13];
  const float* w2 = (const float*)d_in[14];
  const float* b2 = (const float*)d_in[15];
  float* out = (float*)d_out;

  char* base = (char*)d_ws;
  float* xd    = (float*)(base);                  // [0,4) MB
  float* hbuf  = (float*)(base + (4u << 20));     // [4,12) MB
  short* xb    = (short*)(base + (12u << 20));
  short* qb16  = (short*)(base + (14u << 20));
  short* kb16  = (short*)(base + (16u << 20));
  short* vTb   = (short*)(base + (18u << 20));
  short* attnb = (short*)(base + (20u << 20));
  float* psum  = (float*)(base + (22u << 20));    // [512][64]
  float* psq   = psum + 32768;
  float* beff  = psq + 32768;                     // 18*512 fp32
  unsigned* bar = (unsigned*)(base + (23u << 20));
  short* wbuf  = (short*)(base + (24u << 20));    // 18*655360 shorts = 23.6 MB

  hipMemsetAsync(bar, 0, 2 * sizeof(unsigned), stream);
  swap_copy_in<<<1024, 256, 0, stream>>>(desc, xd, xb);
  wconv<<<112 * 18, 256, 0, stream>>>(qw, kw, vw, w1, w2, wbuf, 0);
  wfuse<<<32 * 18, 256, 0, stream>>>(ow, w1, wbuf, 0);
  bfuse<<<18, 256, 0, stream>>>(ob, w1, b1, beff, 0);

  MegaArgs ha;
  ha.mask = mask; ha.qb = qb; ha.kb = kb; ha.vb = vb;
  ha.b2 = b2; ha.bn_g = bn_g; ha.bn_b = bn_b;
  ha.xd = xd; ha.xb = xb;
  ha.qb16 = qb16; ha.kb16 = kb16; ha.vTb = vTb; ha.attnb = attnb;
  ha.hbuf = hbuf; ha.psum = psum; ha.psq = psq; ha.beff = beff;
  ha.wbuf = wbuf; ha.bar = bar;
  mega<<<256, 256, 0, stream>>>(ha);

  swap_copy_out<<<1024, 256, 0, stream>>>(xd, out);
}

// Round 8
// 1370.206 us; speedup vs baseline: 3.8717x; 3.8717x over previous
//
#include <hip/hip_runtime.h>

// B=2, streams=2, N=1024, D=256, H=4, DH=64, L=18
// Row layout: r = s*2048 + b*1024 + n  (M=4096 rows)
// bf16 MFMA 16x16x32: A-frag lane=A[m=lane&15][k=quad*8+j]; B-frag B[k=quad*8+j][n=lane&15]
// C/D: col=lane&15, row=quad*4+reg
// LDS XOR swizzle: 16B chunk c of row r stored at slot (c ^ (r&7)).

typedef __attribute__((ext_vector_type(8))) short bf16x8;
typedef __attribute__((ext_vector_type(4))) short bf16x4;
typedef __attribute__((ext_vector_type(4))) float floatx4;

__device__ __forceinline__ short f2b(float f) {   // fp32 -> bf16 RNE
  unsigned u = __builtin_bit_cast(unsigned, f);
  unsigned r = (u + 0x7FFFu + ((u >> 16) & 1u)) >> 16;
  return (short)r;
}
__device__ __forceinline__ unsigned pack2(float a, float b) {
  return (unsigned)(unsigned short)f2b(a) | ((unsigned)(unsigned short)f2b(b) << 16);
}

__device__ __forceinline__ void gl2lds16(const void* g, void* l) {
  __builtin_amdgcn_global_load_lds(
      (const __attribute__((address_space(1))) unsigned*)g,
      (__attribute__((address_space(3))) unsigned*)l, 16, 0, 0);
}

__device__ __forceinline__ floatx4 mfma16_bf16(bf16x4 a, bf16x4 b, floatx4 c) {
#if __has_builtin(__builtin_amdgcn_mfma_f32_16x16x16_bf16)
  return __builtin_amdgcn_mfma_f32_16x16x16_bf16(a, b, c, 0, 0, 0);
#elif __has_builtin(__builtin_amdgcn_mfma_f32_16x16x16bf16_1k)
  return __builtin_amdgcn_mfma_f32_16x16x16bf16_1k(a, b, c, 0, 0, 0);
#else
  asm volatile("v_mfma_f32_16x16x16_bf16 %0, %1, %2, %0" : "+v"(c) : "v"(a), "v"(b));
  return c;
#endif
}

// ---------- input copy with (s,b) swap; writes fp32 residual + bf16 copy
__global__ __launch_bounds__(256) void swap_copy_in(const float* __restrict__ src,
                                                    float* __restrict__ xd,
                                                    short* __restrict__ xb) {
  int idx = blockIdx.x * 256 + threadIdx.x;
  int fi = idx << 2;
  int hi = (fi >> 19) & 1;
  int lo = (fi >> 18) & 1;
  int sj = (fi & ~(3 << 18)) | (lo << 19) | (hi << 18);
  float4 v = *(const float4*)&src[sj];
  *(float4*)&xd[fi] = v;
  uint2 uu; uu.x = pack2(v.x, v.y); uu.y = pack2(v.z, v.w);
  *(uint2*)&xb[fi] = uu;
}

// ---------- merged weight prep: wconv (2016) | wfuse (576) | bfuse (18)
// per-layer wbuf (shorts): qwt@0 kwt@65536 vwt@131072 w1t@262144(512x512) w2t@524288
__global__ __launch_bounds__(256) void wprep(
    const float* __restrict__ qw, const float* __restrict__ kw,
    const float* __restrict__ vw, const float* __restrict__ ow,
    const float* __restrict__ w1, const float* __restrict__ w2,
    const float* __restrict__ ob, const float* __restrict__ b1,
    short* __restrict__ wbuf, float* __restrict__ beff) {
  __shared__ float SH[64 * 65];
  int blk = blockIdx.x;
  int t = threadIdx.x;
  if (blk < 2016) {
    // ---- transpose+convert Wt[n][k]
    float (*T)[65] = (float(*)[65])SH;
    int layer = blk / 112;
    int sub = blk % 112;
    const float* W; int Kd, Nd, k0, n0; size_t ooff;
    if (sub < 48) {
      int wsel = sub >> 4; int tt = sub & 15;
      k0 = (tt >> 2) * 64; n0 = (tt & 3) * 64; Kd = 256; Nd = 256;
      W = (wsel == 0 ? qw : wsel == 1 ? kw : vw) + (size_t)layer * 65536;
      ooff = (size_t)wsel * 65536;
    } else if (sub < 80) {
      int tt = sub - 48; k0 = (tt >> 3) * 64; n0 = (tt & 7) * 64;   // top half of w1
      Kd = 512; Nd = 512; W = w1 + (size_t)layer * 262144; ooff = 262144;
    } else {
      int tt = sub - 80; k0 = (tt >> 2) * 64; n0 = (tt & 3) * 64;
      Kd = 512; Nd = 256; W = w2 + (size_t)layer * 131072; ooff = 524288;
    }
    short* out = wbuf + (size_t)layer * 655360 + ooff;
    int r = t >> 4, c4 = (t & 15) * 4;
#pragma unroll
    for (int rr = 0; rr < 4; ++rr) {
      float4 v = *(const float4*)&W[(size_t)(k0 + r + rr * 16) * Nd + n0 + c4];
      T[r + rr * 16][c4 + 0] = v.x; T[r + rr * 16][c4 + 1] = v.y;
      T[r + rr * 16][c4 + 2] = v.z; T[r + rr * 16][c4 + 3] = v.w;
    }
    __syncthreads();
    int n = t >> 2, kc = (t & 3) * 16;
    unsigned u[8];
#pragma unroll
    for (int j2 = 0; j2 < 8; ++j2)
      u[j2] = pack2(T[kc + 2 * j2][n], T[kc + 2 * j2 + 1][n]);
    short* op = &out[(size_t)(n0 + n) * Kd + k0 + kc];
    uint4 o1; o1.x = u[0]; o1.y = u[1]; o1.z = u[2]; o1.w = u[3];
    uint4 o2; o2.x = u[4]; o2.y = u[5]; o2.z = u[6]; o2.w = u[7];
    *(uint4*)&op[0] = o1;
    *(uint4*)&op[8] = o2;
  } else if (blk < 2016 + 576) {
    // ---- fused weight F = ow @ w1[256:512]; F^T into w1t[n][256+k']
    float (*As)[64] = (float(*)[64])SH;
    float (*Bs)[65] = (float(*)[65])(SH + 1024);
    int tt = blk - 2016;
    int layer = tt / 32;
    int sub = tt % 32;
    int n0 = (sub & 7) * 64, kp0 = (sub >> 3) * 64;
    const float* A = ow + (size_t)layer * 65536 + (size_t)kp0 * 256;
    const float* B = w1 + (size_t)layer * 262144 + 256 * 512 + n0;
    const int tx = t & 15, ty = t >> 4;
    const int a_r = t >> 2, a_k = (t & 3) << 2;
    const int b_k = t >> 4, b_n = (t & 15) << 2;
    float acc[4][4];
#pragma unroll
    for (int i = 0; i < 4; ++i)
#pragma unroll
      for (int j = 0; j < 4; ++j) acc[i][j] = 0.f;
    for (int i0 = 0; i0 < 256; i0 += 16) {
      float4 av = *(const float4*)&A[(size_t)a_r * 256 + i0 + a_k];
      float4 bv = *(const float4*)&B[(size_t)(i0 + b_k) * 512 + b_n];
      __syncthreads();
      As[a_k + 0][a_r] = av.x; As[a_k + 1][a_r] = av.y;
      As[a_k + 2][a_r] = av.z; As[a_k + 3][a_r] = av.w;
      *(float4*)&Bs[b_k][b_n] = bv;
      __syncthreads();
#pragma unroll
      for (int kk = 0; kk < 16; ++kk) {
        float4 a4 = *(const float4*)&As[kk][ty << 2];
        float4 b4 = *(const float4*)&Bs[kk][tx << 2];
        float aa[4] = {a4.x, a4.y, a4.z, a4.w};
        float bb[4] = {b4.x, b4.y, b4.z, b4.w};
#pragma unroll
        for (int i = 0; i < 4; ++i)
#pragma unroll
          for (int j = 0; j < 4; ++j) acc[i][j] += aa[i] * bb[j];
      }
    }
    short* w1t = wbuf + (size_t)layer * 655360 + 262144;
#pragma unroll
    for (int i = 0; i < 4; ++i)
#pragma unroll
      for (int j = 0; j < 4; ++j)
        w1t[(size_t)(n0 + tx * 4 + j) * 512 + 256 + kp0 + ty * 4 + i] = f2b(acc[i][j]);
  } else {
    // ---- fused bias beff[l][n] = b1[l][n] + sum_i ob[l][i]*w1[l][256+i][n]
    int layer = blk - (2016 + 576);
    const float* obL = ob + (size_t)layer * 256;
    const float* w1L = w1 + (size_t)layer * 262144 + 256 * 512;
    float* be = beff + (size_t)layer * 512;
#pragma unroll
    for (int cc = 0; cc < 2; ++cc) {
      int n = t + cc * 256;
      float s = b1[(size_t)layer * 512 + n];
      for (int i = 0; i < 256; ++i) s += obL[i] * w1L[(size_t)i * 512 + n];
      be[n] = s;
    }
  }
}

#define GEMM_IDS                                        \
  const int tid = threadIdx.x;                          \
  const int lane = tid & 63, w = tid >> 6;              \
  const int wy = w >> 1, wx = w & 1;                    \
  const int quad = lane >> 4, l16 = lane & 15;          \
  const int lr = lane >> 3;                             \
  const int lcs = (((lane & 7) ^ lr) & 7) * 8;          \
  const floatx4 z4 = {0.f, 0.f, 0.f, 0.f};

// swizzled MFMA K-step (BM=64, BN=128, wave-tile 32x64)
__device__ __forceinline__ void mfma_step_sw(const short* As, const short* Bs,
                                             int wy, int wx, int quad, int l16,
                                             floatx4 acc[2][4]) {
#pragma unroll
  for (int kk = 0; kk < 2; ++kk) {
    const int sw = (((kk * 4 + quad) ^ (l16 & 7)) * 8);
    bf16x8 a0 = *(const bf16x8*)&As[(wy * 32 + l16) * 64 + sw];
    bf16x8 a1 = *(const bf16x8*)&As[(wy * 32 + 16 + l16) * 64 + sw];
    bf16x8 b[4];
#pragma unroll
    for (int ni = 0; ni < 4; ++ni)
      b[ni] = *(const bf16x8*)&Bs[(wx * 64 + ni * 16 + l16) * 64 + sw];
#pragma unroll
    for (int ni = 0; ni < 4; ++ni) {
      acc[0][ni] = __builtin_amdgcn_mfma_f32_16x16x32_bf16(a0, b[ni], acc[0][ni], 0, 0, 0);
      acc[1][ni] = __builtin_amdgcn_mfma_f32_16x16x32_bf16(a1, b[ni], acc[1][ni], 0, 0, 0);
    }
  }
}

// swizzled MFMA K-step (BM=64, BN=64, wave-tile 32x32)
__device__ __forceinline__ void mfma_step_sw64(const short* As, const short* Bs,
                                               int wy, int wx, int quad, int l16,
                                               floatx4 acc[2][2]) {
#pragma unroll
  for (int kk = 0; kk < 2; ++kk) {
    const int sw = (((kk * 4 + quad) ^ (l16 & 7)) * 8);
    bf16x8 a0 = *(const bf16x8*)&As[(wy * 32 + l16) * 64 + sw];
    bf16x8 a1 = *(const bf16x8*)&As[(wy * 32 + 16 + l16) * 64 + sw];
    bf16x8 b[2];
#pragma unroll
    for (int ni = 0; ni < 2; ++ni)
      b[ni] = *(const bf16x8*)&Bs[(wx * 32 + ni * 16 + l16) * 64 + sw];
#pragma unroll
    for (int ni = 0; ni < 2; ++ni) {
      acc[0][ni] = __builtin_amdgcn_mfma_f32_16x16x32_bf16(a0, b[ni], acc[0][ni], 0, 0, 0);
      acc[1][ni] = __builtin_amdgcn_mfma_f32_16x16x32_bf16(a1, b[ni], acc[1][ni], 0, 0, 0);
    }
  }
}

// ---------- fused QKV GEMM: grid (64, 6); v-seg writes V^T
__global__ __launch_bounds__(256) void gemm_qkv(
    const short* __restrict__ xb, const short* __restrict__ wbufL,
    const float* __restrict__ qb_, const float* __restrict__ kb_,
    const float* __restrict__ vb_,
    short* __restrict__ q, short* __restrict__ kout, short* __restrict__ vT,
    int cross) {
  __shared__ short SM[2 * 4096 + 2 * 8192];
  short* As = SM;            // [2][4096]
  short* Bs = SM + 8192;     // [2][8192]
  const int rb = blockIdx.x * 64;
  const int cb = blockIdx.y * 128;
  const int seg = cb >> 8;
  const int cbl = cb & 255;
  int arb = rb;
  if (seg) arb = (rb & 2047) | ((((rb >> 11) ^ cross) & 1) << 11);
  const short* A = xb + (size_t)arb * 256;
  const short* Wt = wbufL + (size_t)seg * 65536 + (size_t)cbl * 256;
  const float* bias = (seg == 0 ? qb_ : seg == 1 ? kb_ : vb_) + cbl;
  GEMM_IDS;
  floatx4 acc[2][4] = {{z4, z4, z4, z4}, {z4, z4, z4, z4}};

#define QKV_STAGE(s, buf)                                                          \
  {                                                                                \
    int k0 = (s) * 64;                                                             \
    gl2lds16(&A[(size_t)(w * 8 + lr) * 256 + k0 + lcs], &As[(buf) * 4096 + (w * 8) * 64]); \
    gl2lds16(&A[(size_t)(32 + w * 8 + lr) * 256 + k0 + lcs], &As[(buf) * 4096 + (32 + w * 8) * 64]); \
    _Pragma("unroll") for (int i = 0; i < 4; ++i)                                  \
      gl2lds16(&Wt[(size_t)(i * 32 + w * 8 + lr) * 256 + k0 + lcs],                \
               &Bs[(buf) * 8192 + (i * 32 + w * 8) * 64]);                         \
  }

  QKV_STAGE(0, 0);
  __syncthreads();
  for (int s = 0; s < 4; ++s) {
    int buf = s & 1;
    if (s < 3) QKV_STAGE(s + 1, buf ^ 1);
    mfma_step_sw(&As[buf * 4096], &Bs[buf * 8192], wy, wx, quad, l16, acc);
    __syncthreads();
  }

  if (seg < 2) {
    short* C = (seg == 0 ? q : kout) + (size_t)rb * 256 + cbl;
#pragma unroll
    for (int mi = 0; mi < 2; ++mi)
#pragma unroll
      for (int ni = 0; ni < 4; ++ni) {
        int col = wx * 64 + ni * 16 + l16;
        float bc = bias[col];
#pragma unroll
        for (int reg = 0; reg < 4; ++reg) {
          int row = wy * 32 + mi * 16 + quad * 4 + reg;
          C[(size_t)row * 256 + col] = f2b(acc[mi][ni][reg] + bc);
        }
      }
  } else {
    short* T = SM + w * 2560;       // 64 dims x 40 (pad), wave-local
    const int sb = rb >> 10;
    const int hh = (cbl >> 6) + wx;
    const int z = sb * 4 + hh;
#pragma unroll
    for (int mi = 0; mi < 2; ++mi)
#pragma unroll
      for (int ni = 0; ni < 4; ++ni) {
        int col = wx * 64 + ni * 16 + l16;
        float bc = bias[col];
#pragma unroll
        for (int reg = 0; reg < 4; ++reg)
          T[(ni * 16 + l16) * 40 + mi * 16 + quad * 4 + reg] =
              f2b(acc[mi][ni][reg] + bc);
      }
    short* dst = &vT[((size_t)z * 64 + lane) * 1024 + (rb & 1023) + wy * 32];
#pragma unroll
    for (int c = 0; c < 4; ++c)
      *(uint4*)&dst[c * 8] = *(const uint4*)&T[lane * 40 + c * 8];
  }
#undef QKV_STAGE
}

// ---------- flash attention, S^T/O^T form. grid (qt=32, z=16), 128 threads (2 waves).
__global__ __launch_bounds__(128) void attn_mfma(
    const short* __restrict__ q, const short* __restrict__ k,
    const short* __restrict__ vT, const int* __restrict__ mask,
    short* __restrict__ attnb, int cross) {
  __shared__ short Ks[2 * 4096];
  __shared__ short Vs[2 * 4096];
  __shared__ float Ms[2 * 64];
  const int tid = threadIdx.x;
  const int lane = tid & 63, w = tid >> 6;   // w in {0,1}
  const int quad = lane >> 4, l16 = lane & 15;
  const int lr = lane >> 3;
  const int lcs = (((lane & 7) ^ lr) & 7) * 8;
  const int qt = blockIdx.x;     // 0..31 (32 queries each)
  const int z = blockIdx.y;
  const int sb = z >> 2, h = z & 3;
  const int s = sb >> 1, b = sb & 1;
  const int rowbase = sb * 1024;
  const int* mp = mask + (b * 2 + (s ^ cross)) * 1024;

  const int qrow = qt * 32 + w * 16 + l16;
  bf16x8 qf[2];
#pragma unroll
  for (int kk = 0; kk < 2; ++kk)
    qf[kk] = *(const bf16x8*)&q[(size_t)(rowbase + qrow) * 256 + h * 64 + kk * 32 + quad * 8];

  const floatx4 z4 = {0.f, 0.f, 0.f, 0.f};
  floatx4 o4[4] = {z4, z4, z4, z4};
  float mrun = -1e30f, lsum = 0.f;

#define ATT_STAGE(t, buf)                                                               \
  {                                                                                     \
    int key0 = (t) * 64;                                                                \
    _Pragma("unroll") for (int i = 0; i < 4; ++i) {                                     \
      gl2lds16(&k[(size_t)(rowbase + key0 + w * 32 + i * 8 + lr) * 256 + h * 64 + lcs], \
               &Ks[(buf) * 4096 + (w * 32 + i * 8) * 64]);                              \
      gl2lds16(&vT[((size_t)z * 64 + w * 32 + i * 8 + lr) * 1024 + key0 + lcs],         \
               &Vs[(buf) * 4096 + (w * 32 + i * 8) * 64]);                              \
    }                                                                                   \
    if (tid < 64) Ms[(buf) * 64 + tid] = (mp[key0 + tid] == 0) ? -1.0e9f : 0.f;         \
  }

  ATT_STAGE(0, 0);
  __syncthreads();
  for (int t = 0; t < 16; ++t) {
    int buf = t & 1;
    if (t < 15) ATT_STAGE(t + 1, buf ^ 1);

    // S^T tiles: A=K-frag (m=key), B=Q-frag (n=query)
    floatx4 sA[4] = {z4, z4, z4, z4};
#pragma unroll
    for (int kk = 0; kk < 2; ++kk) {
      const int sw = (((kk * 4 + quad) ^ (l16 & 7)) * 8);
#pragma unroll
      for (int mt = 0; mt < 4; ++mt) {
        bf16x8 kf = *(const bf16x8*)&Ks[buf * 4096 + (mt * 16 + l16) * 64 + sw];
        sA[mt] = __builtin_amdgcn_mfma_f32_16x16x32_bf16(kf, qf[kk], sA[mt], 0, 0, 0);
      }
    }
    float scv[4][4];
    float tmax = -1e30f;
#pragma unroll
    for (int mt = 0; mt < 4; ++mt) {
      float4 mk = *(const float4*)&Ms[buf * 64 + mt * 16 + quad * 4];
      scv[mt][0] = sA[mt][0] * 0.125f + mk.x;
      scv[mt][1] = sA[mt][1] * 0.125f + mk.y;
      scv[mt][2] = sA[mt][2] * 0.125f + mk.z;
      scv[mt][3] = sA[mt][3] * 0.125f + mk.w;
#pragma unroll
      for (int reg = 0; reg < 4; ++reg) tmax = fmaxf(tmax, scv[mt][reg]);
    }
    tmax = fmaxf(tmax, __shfl_xor(tmax, 16));
    tmax = fmaxf(tmax, __shfl_xor(tmax, 32));
    float mnew = fmaxf(mrun, tmax);
    float corr = __expf(mrun - mnew);
    mrun = mnew;
    lsum *= corr;
#pragma unroll
    for (int dt = 0; dt < 4; ++dt)
#pragma unroll
      for (int reg = 0; reg < 4; ++reg) o4[dt][reg] *= corr;

    bf16x4 pb[4];
#pragma unroll
    for (int mt = 0; mt < 4; ++mt) {
      float e0 = __expf(scv[mt][0] - mnew);
      float e1 = __expf(scv[mt][1] - mnew);
      float e2 = __expf(scv[mt][2] - mnew);
      float e3 = __expf(scv[mt][3] - mnew);
      lsum += (e0 + e1) + (e2 + e3);
      union { bf16x4 v; uint2 u; } pu;
      pu.u.x = pack2(e0, e1); pu.u.y = pack2(e2, e3);
      pb[mt] = pu.v;
    }
    // O^T += V^T @ P^T  (P^T straight from registers)
#pragma unroll
    for (int mt = 0; mt < 4; ++mt) {
      const int c2 = mt * 2 + (quad >> 1);
      const int sub = (quad & 1) * 4;
#pragma unroll
      for (int dt = 0; dt < 4; ++dt) {
        bf16x4 vf = *(const bf16x4*)&Vs[buf * 4096 + (dt * 16 + l16) * 64 +
                                        ((c2 ^ (l16 & 7)) * 8) + sub];
        o4[dt] = mfma16_bf16(vf, pb[mt], o4[dt]);
      }
    }
    __syncthreads();
  }
  lsum += __shfl_xor(lsum, 16);
  lsum += __shfl_xor(lsum, 32);
  float inv = 1.f / lsum;
  short* op = &attnb[(size_t)(rowbase + qrow) * 256 + h * 64 + quad * 4];
#pragma unroll
  for (int dt = 0; dt < 4; ++dt) {
    uint2 uu;
    uu.x = pack2(o4[dt][0] * inv, o4[dt][1] * inv);
    uu.y = pack2(o4[dt][2] * inv, o4[dt][3] * inv);
    *(uint2*)&op[dt * 16] = uu;
  }
#undef ATT_STAGE
}

// ---------- W1 GEMM (concat [x | attn], ow pre-fused) + BN column partials. grid (64,4)
__global__ __launch_bounds__(256) void gemm_w1(
    const short* __restrict__ xb, const short* __restrict__ attnb,
    const short* __restrict__ w1t, const float* __restrict__ beff,
    float* __restrict__ hbuf, float* __restrict__ psum, float* __restrict__ psq) {
  __shared__ short SM[2 * 4096 + 2 * 8192];
  __shared__ float Ps[2][2][128];
  short* As = SM;
  short* Bs = SM + 8192;
  const int rb = blockIdx.x * 64, cb = blockIdx.y * 128;
  GEMM_IDS;
  floatx4 acc[2][4] = {{z4, z4, z4, z4}, {z4, z4, z4, z4}};

#define W1_STAGE(s, buf)                                                            \
  {                                                                                 \
    int k0 = (s) * 64;                                                              \
    const short* Ap = ((s) < 4 ? xb : attnb) + (size_t)rb * 256;                    \
    int kb = k0 & 255;                                                              \
    gl2lds16(&Ap[(size_t)(w * 8 + lr) * 256 + kb + lcs], &As[(buf) * 4096 + (w * 8) * 64]); \
    gl2lds16(&Ap[(size_t)(32 + w * 8 + lr) * 256 + kb + lcs], &As[(buf) * 4096 + (32 + w * 8) * 64]); \
    _Pragma("unroll") for (int i = 0; i < 4; ++i)                                   \
      gl2lds16(&w1t[(size_t)(cb + i * 32 + w * 8 + lr) * 512 + k0 + lcs],           \
               &Bs[(buf) * 8192 + (i * 32 + w * 8) * 64]);                          \
  }

  W1_STAGE(0, 0);
  __syncthreads();
  for (int s = 0; s < 8; ++s) {
    int buf = s & 1;
    if (s < 7) W1_STAGE(s + 1, buf ^ 1);
    mfma_step_sw(&As[buf * 4096], &Bs[buf * 8192], wy, wx, quad, l16, acc);
    __syncthreads();
  }
  float colsum[4], colsq[4];
#pragma unroll
  for (int ni = 0; ni < 4; ++ni) { colsum[ni] = 0.f; colsq[ni] = 0.f; }
#pragma unroll
  for (int mi = 0; mi < 2; ++mi)
#pragma unroll
    for (int ni = 0; ni < 4; ++ni) {
      int col = wx * 64 + ni * 16 + l16;
      float bc = beff[cb + col];
#pragma unroll
      for (int reg = 0; reg < 4; ++reg) {
        int row = rb + wy * 32 + mi * 16 + quad * 4 + reg;
        float val = acc[mi][ni][reg] + bc;
        hbuf[(size_t)row * 512 + cb + col] = val;
        colsum[ni] += val; colsq[ni] += val * val;
      }
    }
#pragma unroll
  for (int ni = 0; ni < 4; ++ni)
#pragma unroll
    for (int d = 16; d < 64; d <<= 1) {
      colsum[ni] += __shfl_xor(colsum[ni], d);
      colsq[ni]  += __shfl_xor(colsq[ni], d);
    }
  if (quad == 0) {
#pragma unroll
    for (int ni = 0; ni < 4; ++ni) {
      Ps[wy][0][wx * 64 + ni * 16 + l16] = colsum[ni];
      Ps[wy][1][wx * 64 + ni * 16 + l16] = colsq[ni];
    }
  }
  __syncthreads();
  if (tid < 128) {
    psum[(size_t)(cb + tid) * 64 + blockIdx.x] = Ps[0][0][tid] + Ps[1][0][tid];
    psq [(size_t)(cb + tid) * 64 + blockIdx.x] = Ps[0][1][tid] + Ps[1][1][tid];
  }
#undef W1_STAGE
}

// ---------- W2: BN finalize prologue + fused BN/ReLU A-staging + residual.
// BN=64, grid (64,4) = 256 blocks. Last layer also writes swapped output.
__global__ __launch_bounds__(256) void gemm_w2(
    const float* __restrict__ hbuf, const short* __restrict__ w2t,
    const float* __restrict__ b2_, const float* __restrict__ psum,
    const float* __restrict__ psq, const float* __restrict__ g,
    const float* __restrict__ be, float* __restrict__ xd, short* __restrict__ xb,
    float* __restrict__ outp) {
  __shared__ short SM[2 * 4096 + 2 * 4096];
  __shared__ float s_scale[512], s_shift[512];
  short* As = SM;            // [2][4096]
  short* Bs = SM + 8192;     // [2][4096]
  const int rb = blockIdx.x * 64, cb = blockIdx.y * 64;
  const int str = blockIdx.x >> 5;
  GEMM_IDS;
  floatx4 acc[2][2] = {{z4, z4}, {z4, z4}};
#pragma unroll
  for (int cc = 0; cc < 2; ++cc) {
    int c = tid + cc * 256;
    float sum = 0.f, sq = 0.f;
#pragma unroll
    for (int g4 = 0; g4 < 8; ++g4) {
      float4 a  = *(const float4*)&psum[(size_t)c * 64 + str * 32 + g4 * 4];
      float4 bq = *(const float4*)&psq [(size_t)c * 64 + str * 32 + g4 * 4];
      sum += a.x + a.y + a.z + a.w;
      sq  += bq.x + bq.y + bq.z + bq.w;
    }
    float mean = sum * (1.f / 2048.f);
    float var = sq * (1.f / 2048.f) - mean * mean;
    float rstd = rsqrtf(var + 1e-5f);
    float gs = g[c] * rstd;
    s_scale[c] = gs;
    s_shift[c] = be[c] - mean * gs;
  }
  __syncthreads();

  const int p = tid & 7, ar = tid >> 3;

#define W2_STAGE_A(s, buf)                                                         \
  {                                                                                \
    int k0 = (s) * 64;                                                             \
    _Pragma("unroll") for (int half = 0; half < 2; ++half) {                       \
      int row = ar + half * 32;                                                    \
      int cs = k0 + ((p ^ (row & 7)) * 8);                                         \
      float4 h0 = *(const float4*)&hbuf[(size_t)(rb + row) * 512 + cs];            \
      float4 h1 = *(const float4*)&hbuf[(size_t)(rb + row) * 512 + cs + 4];        \
      float4 sc0 = *(const float4*)&s_scale[cs];                                   \
      float4 sc1 = *(const float4*)&s_scale[cs + 4];                               \
      float4 sh0 = *(const float4*)&s_shift[cs];                                   \
      float4 sh1 = *(const float4*)&s_shift[cs + 4];                               \
      uint4 pk;                                                                    \
      pk.x = pack2(fmaxf(h0.x * sc0.x + sh0.x, 0.f), fmaxf(h0.y * sc0.y + sh0.y, 0.f)); \
      pk.y = pack2(fmaxf(h0.z * sc0.z + sh0.z, 0.f), fmaxf(h0.w * sc0.w + sh0.w, 0.f)); \
      pk.z = pack2(fmaxf(h1.x * sc1.x + sh1.x, 0.f), fmaxf(h1.y * sc1.y + sh1.y, 0.f)); \
      pk.w = pack2(fmaxf(h1.z * sc1.z + sh1.z, 0.f), fmaxf(h1.w * sc1.w + sh1.w, 0.f)); \
      *(uint4*)&As[(buf) * 4096 + row * 64 + p * 8] = pk;                          \
    }                                                                              \
  }
#define W2_STAGE_B(s, buf)                                                         \
  {                                                                                \
    int k0 = (s) * 64;                                                             \
    _Pragma("unroll") for (int i = 0; i < 2; ++i)                                  \
      gl2lds16(&w2t[(size_t)(cb + i * 32 + w * 8 + lr) * 512 + k0 + lcs],          \
               &Bs[(buf) * 4096 + (i * 32 + w * 8) * 64]);                         \
  }

  W2_STAGE_A(0, 0);
  W2_STAGE_B(0, 0);
  __syncthreads();
  for (int s = 0; s < 8; ++s) {
    int buf = s & 1;
    if (s < 7) W2_STAGE_B(s + 1, buf ^ 1);
    mfma_step_sw64(&As[buf * 4096], &Bs[buf * 4096], wy, wx, quad, l16, acc);
    if (s < 7) W2_STAGE_A(s + 1, buf ^ 1);
    __syncthreads();
  }
#pragma unroll
  for (int mi = 0; mi < 2; ++mi)
#pragma unroll
    for (int ni = 0; ni < 2; ++ni) {
      int col = cb + wx * 32 + ni * 16 + l16;
      float bc = b2_[col];
#pragma unroll
      for (int reg = 0; reg < 4; ++reg) {
        int row = rb + wy * 32 + mi * 16 + quad * 4 + reg;
        float r = xd[(size_t)row * 256 + col] + acc[mi][ni][reg] + bc;
        xd[(size_t)row * 256 + col] = r;
        xb[(size_t)row * 256 + col] = f2b(r);
        if (outp) {
          int ss = row >> 11, bb = (row >> 10) & 1, n = row & 1023;
          outp[(size_t)((bb * 2 + ss) * 1024 + n) * 256 + col] = r;
        }
      }
    }
#undef W2_STAGE_A
#undef W2_STAGE_B
}

extern "C" void kernel_launch(void* const* d_in, const int* in_sizes, int n_in,
                              void* d_out, int out_size, void* d_ws, size_t ws_size,
                              hipStream_t stream) {
  (void)in_sizes; (void)n_in; (void)out_size; (void)ws_size;
  const float* desc = (const float*)d_in[0];
  const int*   mask = (const int*)d_in[1];
  const float* qw = (const float*)d_in[2];
  const float* qb = (const float*)d_in[3];
  const float* kw = (const float*)d_in[4];
  const float* kb = (const float*)d_in[5];
  const float* vw = (const float*)d_in[6];
  const float* vb = (const float*)d_in[7];
  const float* ow = (const float*)d_in[8];
  const float* ob = (const float*)d_in[9];
  const float* w1 = (const float*)d_in[10];
  const float* b1 = (const float*)d_in[11];
  const float* bn_g = (const float*)d_in[12];
  const float* bn_b = (const float*)d_in[13];
  const float* w2 = (const float*)d_in[14];
  const float* b2 = (const float*)d_in[15];
  float* out = (float*)d_out;

  char* base = (char*)d_ws;
  float* xd    = (float*)(base);                  // [0,4) MB
  float* hbuf  = (float*)(base + (4u << 20));     // [4,12) MB
  short* xb    = (short*)(base + (12u << 20));
  short* qb16  = (short*)(base + (14u << 20));
  short* kb16  = (short*)(base + (16u << 20));
  short* vTb   = (short*)(base + (18u << 20));
  short* attnb = (short*)(base + (20u << 20));
  float* psum  = (float*)(base + (22u << 20));    // [512][64]
  float* psq   = psum + 32768;
  float* beff  = psq + 32768;                     // 18*512 fp32
  short* wbuf  = (short*)(base + (24u << 20));    // 18*655360 shorts = 23.6 MB

  swap_copy_in<<<1024, 256, 0, stream>>>(desc, xd, xb);
  wprep<<<2016 + 576 + 18, 256, 0, stream>>>(qw, kw, vw, ow, w1, w2, ob, b1,
                                             wbuf, beff);

  for (int i = 0; i < 18; ++i) {
    int cross = i & 1;
    short* wb = wbuf + (size_t)i * 655360;

    gemm_qkv<<<dim3(64, 6), 256, 0, stream>>>(
        xb, wb, qb + (size_t)i * 256, kb + (size_t)i * 256, vb + (size_t)i * 256,
        qb16, kb16, vTb, cross);
    attn_mfma<<<dim3(32, 16), 128, 0, stream>>>(qb16, kb16, vTb, mask, attnb, cross);
    gemm_w1<<<dim3(64, 4), 256, 0, stream>>>(xb, attnb, wb + 262144,
                                             beff + (size_t)i * 512,
                                             hbuf, psum, psq);
    gemm_w2<<<dim3(64, 4), 256, 0, stream>>>(hbuf, wb + 524288,
                                             b2 + (size_t)i * 256, psum, psq,
                                             bn_g + (size_t)i * 512,
                                             bn_b + (size_t)i * 512, xd, xb,
                                             (i == 17) ? out : nullptr);
  }
}

// Round 9
// 1246.097 us; speedup vs baseline: 4.2573x; 1.0996x over previous
//
#include <hip/hip_runtime.h>

// B=2, streams=2, N=1024, D=256, H=4, DH=64, L=18
// Row layout: r = s*2048 + b*1024 + n  (M=4096 rows)
// bf16 MFMA 16x16x32: A-frag lane=A[m=lane&15][k=quad*8+j]; B-frag B[k=quad*8+j][n=lane&15]
// C/D: col=lane&15, row=quad*4+reg
// LDS XOR swizzle: 16B chunk c of row r stored at slot (c ^ (r&7)).

typedef __attribute__((ext_vector_type(8))) short bf16x8;
typedef __attribute__((ext_vector_type(4))) short bf16x4;
typedef __attribute__((ext_vector_type(4))) float floatx4;

__device__ __forceinline__ short f2b(float f) {   // fp32 -> bf16 RNE
  unsigned u = __builtin_bit_cast(unsigned, f);
  unsigned r = (u + 0x7FFFu + ((u >> 16) & 1u)) >> 16;
  return (short)r;
}
__device__ __forceinline__ unsigned pack2(float a, float b) {
  return (unsigned)(unsigned short)f2b(a) | ((unsigned)(unsigned short)f2b(b) << 16);
}

__device__ __forceinline__ void gl2lds16(const void* g, void* l) {
  __builtin_amdgcn_global_load_lds(
      (const __attribute__((address_space(1))) unsigned*)g,
      (__attribute__((address_space(3))) unsigned*)l, 16, 0, 0);
}

__device__ __forceinline__ floatx4 mfma16_bf16(bf16x4 a, bf16x4 b, floatx4 c) {
#if __has_builtin(__builtin_amdgcn_mfma_f32_16x16x16_bf16)
  return __builtin_amdgcn_mfma_f32_16x16x16_bf16(a, b, c, 0, 0, 0);
#elif __has_builtin(__builtin_amdgcn_mfma_f32_16x16x16bf16_1k)
  return __builtin_amdgcn_mfma_f32_16x16x16bf16_1k(a, b, c, 0, 0, 0);
#else
  asm volatile("v_mfma_f32_16x16x16_bf16 %0, %1, %2, %0" : "+v"(c) : "v"(a), "v"(b));
  return c;
#endif
}

// ---------- merged prep kernel:
// blocks [0,576): wfuse  F = ow @ w1[256:512]; F^T into w1t[n][256+k']
// blocks [576,2592): wconv transpose+convert Wt[n][k] (LDS-free)
// blocks [2592,2736): bfuse (parallel)
// blocks [2736,3760): input swap-copy (fp32 residual + bf16)
// per-layer wbuf (shorts): qwt@0 kwt@65536 vwt@131072 w1t@262144(512x512) w2t@524288
__global__ __launch_bounds__(256) void wprep(
    const float* __restrict__ qw, const float* __restrict__ kw,
    const float* __restrict__ vw, const float* __restrict__ ow,
    const float* __restrict__ w1, const float* __restrict__ w2,
    const float* __restrict__ ob, const float* __restrict__ b1,
    short* __restrict__ wbuf, float* __restrict__ beff,
    const float* __restrict__ desc, float* __restrict__ xd,
    short* __restrict__ xb) {
  __shared__ float SH[2080];
  int blk = blockIdx.x;
  int t = threadIdx.x;
  if (blk < 576) {
    // ---- wfuse: fp32 SIMT 64x64 tile over K=256
    float (*As)[64] = (float(*)[64])SH;
    float (*Bs)[65] = (float(*)[65])(SH + 1024);
    int layer = blk / 32;
    int sub = blk % 32;
    int n0 = (sub & 7) * 64, kp0 = (sub >> 3) * 64;
    const float* A = ow + (size_t)layer * 65536 + (size_t)kp0 * 256;  // [kp][i]
    const float* B = w1 + (size_t)layer * 262144 + 256 * 512 + n0;   // [i][n]
    const int tx = t & 15, ty = t >> 4;
    const int a_r = t >> 2, a_k = (t & 3) << 2;
    const int b_k = t >> 4, b_n = (t & 15) << 2;
    float acc[4][4];
#pragma unroll
    for (int i = 0; i < 4; ++i)
#pragma unroll
      for (int j = 0; j < 4; ++j) acc[i][j] = 0.f;
    for (int i0 = 0; i0 < 256; i0 += 16) {
      float4 av = *(const float4*)&A[(size_t)a_r * 256 + i0 + a_k];
      float4 bv = *(const float4*)&B[(size_t)(i0 + b_k) * 512 + b_n];
      __syncthreads();
      As[a_k + 0][a_r] = av.x; As[a_k + 1][a_r] = av.y;
      As[a_k + 2][a_r] = av.z; As[a_k + 3][a_r] = av.w;
      *(float4*)&Bs[b_k][b_n] = bv;
      __syncthreads();
#pragma unroll
      for (int kk = 0; kk < 16; ++kk) {
        float4 a4 = *(const float4*)&As[kk][ty << 2];
        float4 b4 = *(const float4*)&Bs[kk][tx << 2];
        float aa[4] = {a4.x, a4.y, a4.z, a4.w};
        float bb[4] = {b4.x, b4.y, b4.z, b4.w};
#pragma unroll
        for (int i = 0; i < 4; ++i)
#pragma unroll
          for (int j = 0; j < 4; ++j) acc[i][j] += aa[i] * bb[j];
      }
    }
    short* w1t = wbuf + (size_t)layer * 655360 + 262144;
#pragma unroll
    for (int i = 0; i < 4; ++i)
#pragma unroll
      for (int j = 0; j < 4; ++j)
        w1t[(size_t)(n0 + tx * 4 + j) * 512 + 256 + kp0 + ty * 4 + i] = f2b(acc[i][j]);
  } else if (blk < 2592) {
    // ---- wconv: LDS-free transpose+convert of one 64x64 tile
    int sub2 = blk - 576;
    int layer = sub2 / 112;
    int sub = sub2 % 112;
    const float* W; int Kd, Nd, k0, n0; size_t ooff;
    if (sub < 48) {
      int wsel = sub >> 4; int tt = sub & 15;
      k0 = (tt >> 2) * 64; n0 = (tt & 3) * 64; Kd = 256; Nd = 256;
      W = (wsel == 0 ? qw : wsel == 1 ? kw : vw) + (size_t)layer * 65536;
      ooff = (size_t)wsel * 65536;
    } else if (sub < 80) {
      int tt = sub - 48; k0 = (tt >> 3) * 64; n0 = (tt & 7) * 64;   // top half of w1
      Kd = 512; Nd = 512; W = w1 + (size_t)layer * 262144; ooff = 262144;
    } else {
      int tt = sub - 80; k0 = (tt >> 2) * 64; n0 = (tt & 3) * 64;
      Kd = 512; Nd = 256; W = w2 + (size_t)layer * 131072; ooff = 524288;
    }
    short* out = wbuf + (size_t)layer * 655360 + ooff;
    const int n = t >> 2;          // 0..63 column within tile
    const int kq = t & 3;          // k-quarter (16 k's each)
    float v[16];
#pragma unroll
    for (int kk = 0; kk < 16; ++kk)
      v[kk] = W[(size_t)(k0 + kq * 16 + kk) * Nd + n0 + n];
    unsigned u[8];
#pragma unroll
    for (int j2 = 0; j2 < 8; ++j2) u[j2] = pack2(v[2 * j2], v[2 * j2 + 1]);
    short* op = &out[(size_t)(n0 + n) * Kd + k0 + kq * 16];
    uint4 o1; o1.x = u[0]; o1.y = u[1]; o1.z = u[2]; o1.w = u[3];
    uint4 o2; o2.x = u[4]; o2.y = u[5]; o2.z = u[6]; o2.w = u[7];
    *(uint4*)&op[0] = o1;
    *(uint4*)&op[8] = o2;
  } else if (blk < 2736) {
    // ---- bfuse parallel: beff[l][n] = b1[l][n] + sum_i ob[l][i]*w1[l][256+i][n]
    int bb = blk - 2592;
    int layer = bb >> 3;
    int n0 = (bb & 7) * 64;
    const float* obL = ob + (size_t)layer * 256;
    const float* w1L = w1 + (size_t)layer * 262144 + 256 * 512;
    int n = n0 + (t & 63);
    int part = t >> 6;
    float s = 0.f;
    for (int i = part * 64; i < part * 64 + 64; ++i)
      s += obL[i] * w1L[(size_t)i * 512 + n];
    SH[part * 64 + (t & 63)] = s;
    __syncthreads();
    if (t < 64) {
      float tot = SH[t] + SH[64 + t] + SH[128 + t] + SH[192 + t] +
                  b1[(size_t)layer * 512 + n0 + t];
      beff[(size_t)layer * 512 + n0 + t] = tot;
    }
  } else {
    // ---- input copy with (s,b) swap
    int idx = (blk - 2736) * 256 + t;
    int fi = idx << 2;
    int hi = (fi >> 19) & 1;
    int lo = (fi >> 18) & 1;
    int sj = (fi & ~(3 << 18)) | (lo << 19) | (hi << 18);
    float4 v = *(const float4*)&desc[sj];
    *(float4*)&xd[fi] = v;
    uint2 uu; uu.x = pack2(v.x, v.y); uu.y = pack2(v.z, v.w);
    *(uint2*)&xb[fi] = uu;
  }
}

#define GEMM_IDS                                        \
  const int tid = threadIdx.x;                          \
  const int lane = tid & 63, w = tid >> 6;              \
  const int wy = w >> 1, wx = w & 1;                    \
  const int quad = lane >> 4, l16 = lane & 15;          \
  const int lr = lane >> 3;                             \
  const int lcs = (((lane & 7) ^ lr) & 7) * 8;          \
  const floatx4 z4 = {0.f, 0.f, 0.f, 0.f};

// swizzled MFMA K-step (BM=64, BN=128, wave-tile 32x64)
__device__ __forceinline__ void mfma_step_sw(const short* As, const short* Bs,
                                             int wy, int wx, int quad, int l16,
                                             floatx4 acc[2][4]) {
#pragma unroll
  for (int kk = 0; kk < 2; ++kk) {
    const int sw = (((kk * 4 + quad) ^ (l16 & 7)) * 8);
    bf16x8 a0 = *(const bf16x8*)&As[(wy * 32 + l16) * 64 + sw];
    bf16x8 a1 = *(const bf16x8*)&As[(wy * 32 + 16 + l16) * 64 + sw];
    bf16x8 b[4];
#pragma unroll
    for (int ni = 0; ni < 4; ++ni)
      b[ni] = *(const bf16x8*)&Bs[(wx * 64 + ni * 16 + l16) * 64 + sw];
#pragma unroll
    for (int ni = 0; ni < 4; ++ni) {
      acc[0][ni] = __builtin_amdgcn_mfma_f32_16x16x32_bf16(a0, b[ni], acc[0][ni], 0, 0, 0);
      acc[1][ni] = __builtin_amdgcn_mfma_f32_16x16x32_bf16(a1, b[ni], acc[1][ni], 0, 0, 0);
    }
  }
}

// swizzled MFMA K-step (BM=64, BN=64, wave-tile 32x32)
__device__ __forceinline__ void mfma_step_sw64(const short* As, const short* Bs,
                                               int wy, int wx, int quad, int l16,
                                               floatx4 acc[2][2]) {
#pragma unroll
  for (int kk = 0; kk < 2; ++kk) {
    const int sw = (((kk * 4 + quad) ^ (l16 & 7)) * 8);
    bf16x8 a0 = *(const bf16x8*)&As[(wy * 32 + l16) * 64 + sw];
    bf16x8 a1 = *(const bf16x8*)&As[(wy * 32 + 16 + l16) * 64 + sw];
    bf16x8 b[2];
#pragma unroll
    for (int ni = 0; ni < 2; ++ni)
      b[ni] = *(const bf16x8*)&Bs[(wx * 32 + ni * 16 + l16) * 64 + sw];
#pragma unroll
    for (int ni = 0; ni < 2; ++ni) {
      acc[0][ni] = __builtin_amdgcn_mfma_f32_16x16x32_bf16(a0, b[ni], acc[0][ni], 0, 0, 0);
      acc[1][ni] = __builtin_amdgcn_mfma_f32_16x16x32_bf16(a1, b[ni], acc[1][ni], 0, 0, 0);
    }
  }
}

// ---------- fused QKV GEMM: grid (64, 6); v-seg writes V^T
__global__ __launch_bounds__(256) void gemm_qkv(
    const short* __restrict__ xb, const short* __restrict__ wbufL,
    const float* __restrict__ qb_, const float* __restrict__ kb_,
    const float* __restrict__ vb_,
    short* __restrict__ q, short* __restrict__ kout, short* __restrict__ vT,
    int cross) {
  __shared__ short SM[2 * 4096 + 2 * 8192];
  short* As = SM;            // [2][4096]
  short* Bs = SM + 8192;     // [2][8192]
  const int rb = blockIdx.x * 64;
  const int cb = blockIdx.y * 128;
  const int seg = cb >> 8;
  const int cbl = cb & 255;
  int arb = rb;
  if (seg) arb = (rb & 2047) | ((((rb >> 11) ^ cross) & 1) << 11);
  const short* A = xb + (size_t)arb * 256;
  const short* Wt = wbufL + (size_t)seg * 65536 + (size_t)cbl * 256;
  const float* bias = (seg == 0 ? qb_ : seg == 1 ? kb_ : vb_) + cbl;
  GEMM_IDS;
  floatx4 acc[2][4] = {{z4, z4, z4, z4}, {z4, z4, z4, z4}};

#define QKV_STAGE(s, buf)                                                          \
  {                                                                                \
    int k0 = (s) * 64;                                                             \
    gl2lds16(&A[(size_t)(w * 8 + lr) * 256 + k0 + lcs], &As[(buf) * 4096 + (w * 8) * 64]); \
    gl2lds16(&A[(size_t)(32 + w * 8 + lr) * 256 + k0 + lcs], &As[(buf) * 4096 + (32 + w * 8) * 64]); \
    _Pragma("unroll") for (int i = 0; i < 4; ++i)                                  \
      gl2lds16(&Wt[(size_t)(i * 32 + w * 8 + lr) * 256 + k0 + lcs],                \
               &Bs[(buf) * 8192 + (i * 32 + w * 8) * 64]);                         \
  }

  QKV_STAGE(0, 0);
  __syncthreads();
  for (int s = 0; s < 4; ++s) {
    int buf = s & 1;
    if (s < 3) QKV_STAGE(s + 1, buf ^ 1);
    mfma_step_sw(&As[buf * 4096], &Bs[buf * 8192], wy, wx, quad, l16, acc);
    __syncthreads();
  }

  if (seg < 2) {
    short* C = (seg == 0 ? q : kout) + (size_t)rb * 256 + cbl;
#pragma unroll
    for (int mi = 0; mi < 2; ++mi)
#pragma unroll
      for (int ni = 0; ni < 4; ++ni) {
        int col = wx * 64 + ni * 16 + l16;
        float bc = bias[col];
#pragma unroll
        for (int reg = 0; reg < 4; ++reg) {
          int row = wy * 32 + mi * 16 + quad * 4 + reg;
          C[(size_t)row * 256 + col] = f2b(acc[mi][ni][reg] + bc);
        }
      }
  } else {
    short* T = SM + w * 2560;       // 64 dims x 40 (pad), wave-local
    const int sb = rb >> 10;
    const int hh = (cbl >> 6) + wx;
    const int z = sb * 4 + hh;
#pragma unroll
    for (int mi = 0; mi < 2; ++mi)
#pragma unroll
      for (int ni = 0; ni < 4; ++ni) {
        int col = wx * 64 + ni * 16 + l16;
        float bc = bias[col];
#pragma unroll
        for (int reg = 0; reg < 4; ++reg)
          T[(ni * 16 + l16) * 40 + mi * 16 + quad * 4 + reg] =
              f2b(acc[mi][ni][reg] + bc);
      }
    short* dst = &vT[((size_t)z * 64 + lane) * 1024 + (rb & 1023) + wy * 32];
#pragma unroll
    for (int c = 0; c < 4; ++c)
      *(uint4*)&dst[c * 8] = *(const uint4*)&T[lane * 40 + c * 8];
  }
#undef QKV_STAGE
}

// ---------- flash attention, S^T/O^T form. grid (qt=16, z=16), 256 threads (4 waves).
__global__ __launch_bounds__(256) void attn_mfma(
    const short* __restrict__ q, const short* __restrict__ k,
    const short* __restrict__ vT, const int* __restrict__ mask,
    short* __restrict__ attnb, int cross) {
  __shared__ short Ks[2][4096];
  __shared__ short Vs[2][4096];
  __shared__ float Ms[2][64];
  const int tid = threadIdx.x;
  const int lane = tid & 63, w = tid >> 6;
  const int quad = lane >> 4, l16 = lane & 15;
  const int lr = lane >> 3;
  const int lcs = (((lane & 7) ^ lr) & 7) * 8;
  const int qt = blockIdx.x;
  const int z = blockIdx.y;
  const int sb = z >> 2, h = z & 3;
  const int s = sb >> 1, b = sb & 1;
  const int rowbase = sb * 1024;
  const int* mp = mask + (b * 2 + (s ^ cross)) * 1024;

  const int qrow = qt * 64 + w * 16 + l16;      // this lane's query
  bf16x8 qf[2];
#pragma unroll
  for (int kk = 0; kk < 2; ++kk)
    qf[kk] = *(const bf16x8*)&q[(size_t)(rowbase + qrow) * 256 + h * 64 + kk * 32 + quad * 8];

  const floatx4 z4 = {0.f, 0.f, 0.f, 0.f};
  floatx4 o4[4] = {z4, z4, z4, z4};
  float mrun = -1e30f, lsum = 0.f;

#define ATT_STAGE(t, buf)                                                               \
  {                                                                                     \
    int key0 = (t) * 64;                                                                \
    gl2lds16(&k[(size_t)(rowbase + key0 + w * 8 + lr) * 256 + h * 64 + lcs],            \
             &Ks[buf][(w * 8) * 64]);                                                   \
    gl2lds16(&k[(size_t)(rowbase + key0 + 32 + w * 8 + lr) * 256 + h * 64 + lcs],       \
             &Ks[buf][(32 + w * 8) * 64]);                                              \
    gl2lds16(&vT[((size_t)z * 64 + w * 8 + lr) * 1024 + key0 + lcs],                    \
             &Vs[buf][(w * 8) * 64]);                                                   \
    gl2lds16(&vT[((size_t)z * 64 + 32 + w * 8 + lr) * 1024 + key0 + lcs],               \
             &Vs[buf][(32 + w * 8) * 64]);                                              \
    if (tid < 64) Ms[buf][tid] = (mp[key0 + tid] == 0) ? -1.0e9f : 0.f;                 \
  }

  ATT_STAGE(0, 0);
  __syncthreads();
  for (int t = 0; t < 16; ++t) {
    int buf = t & 1;
    if (t < 15) ATT_STAGE(t + 1, buf ^ 1);

    // S^T tiles: A=K-frag (m=key), B=Q-frag (n=query)
    floatx4 sA[4] = {z4, z4, z4, z4};
#pragma unroll
    for (int kk = 0; kk < 2; ++kk) {
      const int sw = (((kk * 4 + quad) ^ (l16 & 7)) * 8);
#pragma unroll
      for (int mt = 0; mt < 4; ++mt) {
        bf16x8 kf = *(const bf16x8*)&Ks[buf][(mt * 16 + l16) * 64 + sw];
        sA[mt] = __builtin_amdgcn_mfma_f32_16x16x32_bf16(kf, qf[kk], sA[mt], 0, 0, 0);
      }
    }
    float scv[4][4];
    float tmax = -1e30f;
#pragma unroll
    for (int mt = 0; mt < 4; ++mt) {
      float4 mk = *(const float4*)&Ms[buf][mt * 16 + quad * 4];
      scv[mt][0] = sA[mt][0] * 0.125f + mk.x;
      scv[mt][1] = sA[mt][1] * 0.125f + mk.y;
      scv[mt][2] = sA[mt][2] * 0.125f + mk.z;
      scv[mt][3] = sA[mt][3] * 0.125f + mk.w;
#pragma unroll
      for (int reg = 0; reg < 4; ++reg) tmax = fmaxf(tmax, scv[mt][reg]);
    }
    tmax = fmaxf(tmax, __shfl_xor(tmax, 16));
    tmax = fmaxf(tmax, __shfl_xor(tmax, 32));
    float mnew = fmaxf(mrun, tmax);
    float corr = __expf(mrun - mnew);
    mrun = mnew;
    lsum *= corr;
#pragma unroll
    for (int dt = 0; dt < 4; ++dt)
#pragma unroll
      for (int reg = 0; reg < 4; ++reg) o4[dt][reg] *= corr;

    bf16x4 pb[4];
#pragma unroll
    for (int mt = 0; mt < 4; ++mt) {
      float e0 = __expf(scv[mt][0] - mnew);
      float e1 = __expf(scv[mt][1] - mnew);
      float e2 = __expf(scv[mt][2] - mnew);
      float e3 = __expf(scv[mt][3] - mnew);
      lsum += (e0 + e1) + (e2 + e3);
      union { bf16x4 v; uint2 u; } pu;
      pu.u.x = pack2(e0, e1); pu.u.y = pack2(e2, e3);
      pb[mt] = pu.v;
    }
    // O^T += V^T @ P^T  (P^T straight from registers)
#pragma unroll
    for (int mt = 0; mt < 4; ++mt) {
      const int c2 = mt * 2 + (quad >> 1);
      const int sub = (quad & 1) * 4;
#pragma unroll
      for (int dt = 0; dt < 4; ++dt) {
        bf16x4 vf = *(const bf16x4*)&Vs[buf][(dt * 16 + l16) * 64 +
                                             ((c2 ^ (l16 & 7)) * 8) + sub];
        o4[dt] = mfma16_bf16(vf, pb[mt], o4[dt]);
      }
    }
    __syncthreads();
  }
  lsum += __shfl_xor(lsum, 16);
  lsum += __shfl_xor(lsum, 32);
  float inv = 1.f / lsum;
  short* op = &attnb[(size_t)(rowbase + qrow) * 256 + h * 64 + quad * 4];
#pragma unroll
  for (int dt = 0; dt < 4; ++dt) {
    uint2 uu;
    uu.x = pack2(o4[dt][0] * inv, o4[dt][1] * inv);
    uu.y = pack2(o4[dt][2] * inv, o4[dt][3] * inv);
    *(uint2*)&op[dt * 16] = uu;
  }
#undef ATT_STAGE
}

// ---------- W1 GEMM (concat [x | attn], ow pre-fused) + BN column partials. grid (64,4)
__global__ __launch_bounds__(256) void gemm_w1(
    const short* __restrict__ xb, const short* __restrict__ attnb,
    const short* __restrict__ w1t, const float* __restrict__ beff,
    float* __restrict__ hbuf, float* __restrict__ psum, float* __restrict__ psq) {
  __shared__ short SM[2 * 4096 + 2 * 8192];
  __shared__ float Ps[2][2][128];
  short* As = SM;
  short* Bs = SM + 8192;
  const int rb = blockIdx.x * 64, cb = blockIdx.y * 128;
  GEMM_IDS;
  floatx4 acc[2][4] = {{z4, z4, z4, z4}, {z4, z4, z4, z4}};

#define W1_STAGE(s, buf)                                                            \
  {                                                                                 \
    int k0 = (s) * 64;                                                              \
    const short* Ap = ((s) < 4 ? xb : attnb) + (size_t)rb * 256;                    \
    int kb = k0 & 255;                                                              \
    gl2lds16(&Ap[(size_t)(w * 8 + lr) * 256 + kb + lcs], &As[(buf) * 4096 + (w * 8) * 64]); \
    gl2lds16(&Ap[(size_t)(32 + w * 8 + lr) * 256 + kb + lcs], &As[(buf) * 4096 + (32 + w * 8) * 64]); \
    _Pragma("unroll") for (int i = 0; i < 4; ++i)                                   \
      gl2lds16(&w1t[(size_t)(cb + i * 32 + w * 8 + lr) * 512 + k0 + lcs],           \
               &Bs[(buf) * 8192 + (i * 32 + w * 8) * 64]);                          \
  }

  W1_STAGE(0, 0);
  __syncthreads();
  for (int s = 0; s < 8; ++s) {
    int buf = s & 1;
    if (s < 7) W1_STAGE(s + 1, buf ^ 1);
    mfma_step_sw(&As[buf * 4096], &Bs[buf * 8192], wy, wx, quad, l16, acc);
    __syncthreads();
  }
  float colsum[4], colsq[4];
#pragma unroll
  for (int ni = 0; ni < 4; ++ni) { colsum[ni] = 0.f; colsq[ni] = 0.f; }
#pragma unroll
  for (int mi = 0; mi < 2; ++mi)
#pragma unroll
    for (int ni = 0; ni < 4; ++ni) {
      int col = wx * 64 + ni * 16 + l16;
      float bc = beff[cb + col];
#pragma unroll
      for (int reg = 0; reg < 4; ++reg) {
        int row = rb + wy * 32 + mi * 16 + quad * 4 + reg;
        float val = acc[mi][ni][reg] + bc;
        hbuf[(size_t)row * 512 + cb + col] = val;
        colsum[ni] += val; colsq[ni] += val * val;
      }
    }
#pragma unroll
  for (int ni = 0; ni < 4; ++ni)
#pragma unroll
    for (int d = 16; d < 64; d <<= 1) {
      colsum[ni] += __shfl_xor(colsum[ni], d);
      colsq[ni]  += __shfl_xor(colsq[ni], d);
    }
  if (quad == 0) {
#pragma unroll
    for (int ni = 0; ni < 4; ++ni) {
      Ps[wy][0][wx * 64 + ni * 16 + l16] = colsum[ni];
      Ps[wy][1][wx * 64 + ni * 16 + l16] = colsq[ni];
    }
  }
  __syncthreads();
  if (tid < 128) {
    psum[(size_t)(cb + tid) * 64 + blockIdx.x] = Ps[0][0][tid] + Ps[1][0][tid];
    psq [(size_t)(cb + tid) * 64 + blockIdx.x] = Ps[0][1][tid] + Ps[1][1][tid];
  }
#undef W1_STAGE
}

// ---------- W2: BN finalize prologue + fused BN/ReLU A-staging + residual.
// BN=64, grid (64,4) = 256 blocks. Last layer also writes swapped output.
__global__ __launch_bounds__(256) void gemm_w2(
    const float* __restrict__ hbuf, const short* __restrict__ w2t,
    const float* __restrict__ b2_, const float* __restrict__ psum,
    const float* __restrict__ psq, const float* __restrict__ g,
    const float* __restrict__ be, float* __restrict__ xd, short* __restrict__ xb,
    float* __restrict__ outp) {
  __shared__ short SM[2 * 4096 + 2 * 4096];
  __shared__ float s_scale[512], s_shift[512];
  short* As = SM;            // [2][4096]
  short* Bs = SM + 8192;     // [2][4096]
  const int rb = blockIdx.x * 64, cb = blockIdx.y * 64;
  const int str = blockIdx.x >> 5;
  GEMM_IDS;
  floatx4 acc[2][2] = {{z4, z4}, {z4, z4}};
#pragma unroll
  for (int cc = 0; cc < 2; ++cc) {
    int c = tid + cc * 256;
    float sum = 0.f, sq = 0.f;
#pragma unroll
    for (int g4 = 0; g4 < 8; ++g4) {
      float4 a  = *(const float4*)&psum[(size_t)c * 64 + str * 32 + g4 * 4];
      float4 bq = *(const float4*)&psq [(size_t)c * 64 + str * 32 + g4 * 4];
      sum += a.x + a.y + a.z + a.w;
      sq  += bq.x + bq.y + bq.z + bq.w;
    }
    float mean = sum * (1.f / 2048.f);
    float var = sq * (1.f / 2048.f) - mean * mean;
    float rstd = rsqrtf(var + 1e-5f);
    float gs = g[c] * rstd;
    s_scale[c] = gs;
    s_shift[c] = be[c] - mean * gs;
  }
  __syncthreads();

  const int p = tid & 7, ar = tid >> 3;

#define W2_STAGE_A(s, buf)                                                         \
  {                                                                                \
    int k0 = (s) * 64;                                                             \
    _Pragma("unroll") for (int half = 0; half < 2; ++half) {                       \
      int row = ar + half * 32;                                                    \
      int cs = k0 + ((p ^ (row & 7)) * 8);                                         \
      float4 h0 = *(const float4*)&hbuf[(size_t)(rb + row) * 512 + cs];            \
      float4 h1 = *(const float4*)&hbuf[(size_t)(rb + row) * 512 + cs + 4];        \
      float4 sc0 = *(const float4*)&s_scale[cs];                                   \
      float4 sc1 = *(const float4*)&s_scale[cs + 4];                               \
      float4 sh0 = *(const float4*)&s_shift[cs];                                   \
      float4 sh1 = *(const float4*)&s_shift[cs + 4];                               \
      uint4 pk;                                                                    \
      pk.x = pack2(fmaxf(h0.x * sc0.x + sh0.x, 0.f), fmaxf(h0.y * sc0.y + sh0.y, 0.f)); \
      pk.y = pack2(fmaxf(h0.z * sc0.z + sh0.z, 0.f), fmaxf(h0.w * sc0.w + sh0.w, 0.f)); \
      pk.z = pack2(fmaxf(h1.x * sc1.x + sh1.x, 0.f), fmaxf(h1.y * sc1.y + sh1.y, 0.f)); \
      pk.w = pack2(fmaxf(h1.z * sc1.z + sh1.z, 0.f), fmaxf(h1.w * sc1.w + sh1.w, 0.f)); \
      *(uint4*)&As[(buf) * 4096 + row * 64 + p * 8] = pk;                          \
    }                                                                              \
  }
#define W2_STAGE_B(s, buf)                                                         \
  {                                                                                \
    int k0 = (s) * 64;                                                             \
    _Pragma("unroll") for (int i = 0; i < 2; ++i)                                  \
      gl2lds16(&w2t[(size_t)(cb + i * 32 + w * 8 + lr) * 512 + k0 + lcs],          \
               &Bs[(buf) * 4096 + (i * 32 + w * 8) * 64]);                         \
  }

  W2_STAGE_A(0, 0);
  W2_STAGE_B(0, 0);
  __syncthreads();
  for (int s = 0; s < 8; ++s) {
    int buf = s & 1;
    if (s < 7) W2_STAGE_B(s + 1, buf ^ 1);
    mfma_step_sw64(&As[buf * 4096], &Bs[buf * 4096], wy, wx, quad, l16, acc);
    if (s < 7) W2_STAGE_A(s + 1, buf ^ 1);
    __syncthreads();
  }
#pragma unroll
  for (int mi = 0; mi < 2; ++mi)
#pragma unroll
    for (int ni = 0; ni < 2; ++ni) {
      int col = cb + wx * 32 + ni * 16 + l16;
      float bc = b2_[col];
#pragma unroll
      for (int reg = 0; reg < 4; ++reg) {
        int row = rb + wy * 32 + mi * 16 + quad * 4 + reg;
        float r = xd[(size_t)row * 256 + col] + acc[mi][ni][reg] + bc;
        xd[(size_t)row * 256 + col] = r;
        xb[(size_t)row * 256 + col] = f2b(r);
        if (outp) {
          int ss = row >> 11, bb = (row >> 10) & 1, n = row & 1023;
          outp[(size_t)((bb * 2 + ss) * 1024 + n) * 256 + col] = r;
        }
      }
    }
#undef W2_STAGE_A
#undef W2_STAGE_B
}

extern "C" void kernel_launch(void* const* d_in, const int* in_sizes, int n_in,
                              void* d_out, int out_size, void* d_ws, size_t ws_size,
                              hipStream_t stream) {
  (void)in_sizes; (void)n_in; (void)out_size; (void)ws_size;
  const float* desc = (const float*)d_in[0];
  const int*   mask = (const int*)d_in[1];
  const float* qw = (const float*)d_in[2];
  const float* qb = (const float*)d_in[3];
  const float* kw = (const float*)d_in[4];
  const float* kb = (const float*)d_in[5];
  const float* vw = (const float*)d_in[6];
  const float* vb = (const float*)d_in[7];
  const float* ow = (const float*)d_in[8];
  const float* ob = (const float*)d_in[9];
  const float* w1 = (const float*)d_in[10];
  const float* b1 = (const float*)d_in[11];
  const float* bn_g = (const float*)d_in[12];
  const float* bn_b = (const float*)d_in[13];
  const float* w2 = (const float*)d_in[14];
  const float* b2 = (const float*)d_in[15];
  float* out = (float*)d_out;

  char* base = (char*)d_ws;
  float* xd    = (float*)(base);                  // [0,4) MB
  float* hbuf  = (float*)(base + (4u << 20));     // [4,12) MB
  short* xb    = (short*)(base + (12u << 20));
  short* qb16  = (short*)(base + (14u << 20));
  short* kb16  = (short*)(base + (16u << 20));
  short* vTb   = (short*)(base + (18u << 20));
  short* attnb = (short*)(base + (20u << 20));
  float* psum  = (float*)(base + (22u << 20));    // [512][64]
  float* psq   = psum + 32768;
  float* beff  = psq + 32768;                     // 18*512 fp32
  short* wbuf  = (short*)(base + (24u << 20));    // 18*655360 shorts = 23.6 MB

  wprep<<<3760, 256, 0, stream>>>(qw, kw, vw, ow, w1, w2, ob, b1,
                                  wbuf, beff, desc, xd, xb);

  for (int i = 0; i < 18; ++i) {
    int cross = i & 1;
    short* wb = wbuf + (size_t)i * 655360;

    gemm_qkv<<<dim3(64, 6), 256, 0, stream>>>(
        xb, wb, qb + (size_t)i * 256, kb + (size_t)i * 256, vb + (size_t)i * 256,
        qb16, kb16, vTb, cross);
    attn_mfma<<<dim3(16, 16), 256, 0, stream>>>(qb16, kb16, vTb, mask, attnb, cross);
    gemm_w1<<<dim3(64, 4), 256, 0, stream>>>(xb, attnb, wb + 262144,
                                             beff + (size_t)i * 512,
                                             hbuf, psum, psq);
    gemm_w2<<<dim3(64, 4), 256, 0, stream>>>(hbuf, wb + 524288,
                                             b2 + (size_t)i * 256, psum, psq,
                                             bn_g + (size_t)i * 512,
                                             bn_b + (size_t)i * 512, xd, xb,
                                             (i == 17) ? out : nullptr);
  }
}